// Round 5
// baseline (8049.433 us; speedup 1.0000x reference)
//
#include <hip/hip_runtime.h>

typedef __bf16 bf16x8 __attribute__((ext_vector_type(8)));
typedef float f32x4 __attribute__((ext_vector_type(4)));
typedef unsigned short u16;
typedef unsigned int u32;
typedef unsigned long long u64;

#define NT 50
#define NB 1024
#define DET 600
#define DP 608        // padded 600 -> 19*32
#define NP 640        // padded 600 -> 5*128
#define EMB 1024
#define OUTW 792
#define GBLK 160      // persistent grid: phase A=160 tiles, phase B=128 slices

__device__ __forceinline__ u16 f2bf(float f) {
  unsigned u = __float_as_uint(f);
  u += 0x7FFFu + ((u >> 16) & 1u);
  return (u16)(u >> 16);
}
__device__ __forceinline__ float bf2f(u16 h) { return __uint_as_float(((unsigned)h) << 16); }
__device__ __forceinline__ float eluf(float x) { return x > 0.f ? x : expm1f(x); }
__device__ __forceinline__ float sigm(float x) { return 1.f / (1.f + expf(-x)); }
__device__ __forceinline__ float softplusf(float x) {
  return fmaxf(x, 0.f) + log1pf(expf(-fabsf(x)));
}

__device__ __forceinline__ void gll16(const void* g, void* l) {
  __builtin_amdgcn_global_load_lds(
      (const __attribute__((address_space(1))) u32*)g,
      (__attribute__((address_space(3))) u32*)l, 16, 0, 0);
}

// Manual grid barrier (sense-reversing, monotone targets). bar[0]=counter, bar[1]=sense.
// Zeroed by hipMemsetAsync each kernel_launch call; targets 1..2*NT, no wrap.
__device__ __forceinline__ void gridbar(u32* bar, u32 target) {
  __syncthreads();
  if (threadIdx.x == 0) {
    __threadfence();  // agent-scope release of all prior stores
    u32 arrived = __hip_atomic_fetch_add(&bar[0], 1u, __ATOMIC_ACQ_REL, __HIP_MEMORY_SCOPE_AGENT);
    if (arrived == GBLK - 1) {
      __hip_atomic_store(&bar[0], 0u, __ATOMIC_RELAXED, __HIP_MEMORY_SCOPE_AGENT);
      __hip_atomic_store(&bar[1], target, __ATOMIC_RELEASE, __HIP_MEMORY_SCOPE_AGENT);
    } else {
      while (__hip_atomic_load(&bar[1], __ATOMIC_ACQUIRE, __HIP_MEMORY_SCOPE_AGENT) < target)
        __builtin_amdgcn_s_sleep(2);
    }
    __threadfence();  // agent-scope acquire before subsequent loads
  }
  __syncthreads();
}

// Swizzled chunk layout for [rows][32] bf16 tiles staged as 16B chunks:
// chunk S holds (row = S>>2, k8 = ((S&3) - ((S>>3)&3)) & 3).
// reader for (row,k8): S = row*4 + ((k8 + (row>>1)) & 3)  -> 2-way banks (free).

// ---------------- persistent RSSM rollout kernel ------------------------------
struct PK {
  const u16 *W6, *Wp1, *Wq1h, *Wp2, *Wq2, *Winp, *QE;
  const float *b_ih, *b_hh, *bp1, *bq1, *bp2, *bq2, *b_in;
  const float *init_deter, *actions, *nonterm, *noise_p, *noise_q;
  u16 *xb, *hb0, *hb1;
  float *out;
  u32 *bar;
};

__global__ __launch_bounds__(256, 1) void rssm_persist(PK p)
{
  __shared__ char smem[65536] __attribute__((aligned(16)));

  const int bid = blockIdx.x, tid = threadIdx.x;
  const int lane = tid & 63, w = tid >> 6;
  const int r16 = lane & 15, k8g = lane >> 4;

  // ----- phase A config (GRU 64x64x6 tile). XCD-affinity mapping: blocks with
  // the same weight n-tile (nx) land on the same XCD (XCD = bid % 8) so each
  // W6 column-tile is pulled into exactly one (nx<8) L2 and stays resident.
  int my, nx;
  if (bid < 128) { my = bid >> 3; nx = bid & 7; }
  else           { my = (bid - 128) >> 1; nx = 8 + (bid & 1); }
  const int Am0 = my * 64, An0 = nx * 64;
  const int wr = w >> 1, wc = w & 1;
  const int srow = tid >> 2;
  const int sk8 = ((tid & 3) - ((tid >> 3) & 3)) & 3;
  const int lo = w * 1024;
  const u16* bw[6];
#pragma unroll
  for (int s = 0; s < 6; s++)
    bw[s] = p.W6 + (size_t)s * NP * DP + (size_t)(An0 + srow) * DP + sk8 * 8;
  const u16* axp = p.xb + (size_t)(Am0 + srow) * DP + sk8 * 8;
  const size_t ahoff = (size_t)(Am0 + srow) * DP + sk8 * 8;

  // ----- phase B config (heads for 16-row slice x head), bid 0..127
  const bool doB = bid < 128;
  const int slice = bid >> 1, head = bid & 1;
  const int Bm0 = slice * 16;
  const u16* W1 = head ? p.Wq1h : p.Wp1;
  const float* b1 = head ? p.bq1 : p.bp1;
  const u16* W2 = head ? p.Wq2 : p.Wp2;
  const float* b2 = head ? p.bq2 : p.bp2;

  u16* ph = (u16*)smem;                    // [16][648] bf16 (cols 600..647 zero)
  float* red = (float*)(smem + 20992);     // [3][64][16] f32
  u16* xin = (u16*)(smem + 33280);         // [16][72] bf16

  for (int t = 0; t < NT; ++t) {
    const u16* hcur = (t & 1) ? p.hb1 : p.hb0;
    u16* hnxt = (t & 1) ? p.hb0 : p.hb1;
    float* out_t = p.out + (size_t)t * NB * OUTW;

    // =================== phase A: GRU ===================
    {
      const u16* ahp = hcur + ahoff;
      auto ldsT = [&](int buf, int tile) -> char* { return smem + buf * 32768 + tile * 4096; };
      f32x4 acc[6][2][2] = {};
      auto stage = [&](int buf, int kc) {
        gll16(axp + kc, ldsT(buf, 0) + lo);
        gll16(ahp + kc, ldsT(buf, 1) + lo);
#pragma unroll
        for (int s = 0; s < 6; s++) gll16(bw[s] + kc, ldsT(buf, 2 + s) + lo);
      };
      auto compute = [&](int buf) {
        bf16x8 ax_[2], ah_[2];
#pragma unroll
        for (int i = 0; i < 2; i++) {
          int row = wr * 32 + i * 16 + r16;
          int S = row * 4 + ((k8g + (row >> 1)) & 3);
          ax_[i] = *(const bf16x8*)(ldsT(buf, 0) + S * 16);
          ah_[i] = *(const bf16x8*)(ldsT(buf, 1) + S * 16);
        }
#pragma unroll
        for (int s = 0; s < 6; s++) {
#pragma unroll
          for (int j = 0; j < 2; j++) {
            int row = wc * 32 + j * 16 + r16;
            int S = row * 4 + ((k8g + (row >> 1)) & 3);
            bf16x8 b = *(const bf16x8*)(ldsT(buf, 2 + s) + S * 16);
#pragma unroll
            for (int i = 0; i < 2; i++)
              acc[s][i][j] = __builtin_amdgcn_mfma_f32_16x16x32_bf16(
                  (s < 3) ? ax_[i] : ah_[i], b, acc[s][i][j], 0, 0, 0);
          }
        }
      };
      stage(0, 0);
      __syncthreads();
      for (int it = 0; it < 19; ++it) {
        if (it + 1 < 19) stage((it + 1) & 1, (it + 1) * 32);
        compute(it & 1);
        __syncthreads();
      }
      const float* dprev = t ? (out_t - (size_t)NB * OUTW) : p.init_deter;
      const int dstr = t ? OUTW : DET;
#pragma unroll
      for (int j = 0; j < 2; j++) {
        int n = An0 + wc * 32 + j * 16 + r16;
        if (n >= DET) {
          if (n < DP) {
#pragma unroll
            for (int i = 0; i < 2; i++) {
              int mb = Am0 + wr * 32 + i * 16 + k8g * 4;
#pragma unroll
              for (int r = 0; r < 4; r++) hnxt[(size_t)(mb + r) * DP + n] = 0;
            }
          }
          continue;
        }
        float bihr = p.b_ih[n], bihz = p.b_ih[600 + n], bihn = p.b_ih[1200 + n];
        float bhhr = p.b_hh[n], bhhz = p.b_hh[600 + n], bhhn = p.b_hh[1200 + n];
#pragma unroll
        for (int i = 0; i < 2; i++) {
          int mb = Am0 + wr * 32 + i * 16 + k8g * 4;
#pragma unroll
          for (int r = 0; r < 4; r++) {
            int m = mb + r;
            float rg = sigm(acc[0][i][j][r] + bihr + acc[3][i][j][r] + bhhr);
            float zg = sigm(acc[1][i][j][r] + bihz + acc[4][i][j][r] + bhhz);
            float ng = tanhf(acc[2][i][j][r] + bihn + rg * (acc[5][i][j][r] + bhhn));
            float h = (1.f - zg) * ng + zg * dprev[(size_t)m * dstr + n];
            out_t[(size_t)m * OUTW + n] = h;
            hnxt[(size_t)m * DP + n] = f2bf(h);
          }
        }
      }
    }
    gridbar(p.bar, 2 * t + 1);

    // =================== phase B: heads + sampling + xnext ===================
    if (doB) {
      const bool donext = (t + 1 < NT);
      const float* noise = (head ? p.noise_q : p.noise_p) + (size_t)t * NB * 32;
      // ---- heads1: [16 rows] x [608 cols], K=608, direct-global frags
      f32x4 a1[10] = {};
#pragma unroll 2
      for (int kc = 0; kc < DP; kc += 32) {
        bf16x8 fa = *(const bf16x8*)&hnxt[(size_t)(Bm0 + r16) * DP + kc + k8g * 8];
#pragma unroll
        for (int i = 0; i < 10; i++) {
          int j = w + i * 4;
          if (j < 38) {
            bf16x8 fb = *(const bf16x8*)&W1[(size_t)(j * 16 + r16) * DP + kc + k8g * 8];
            a1[i] = __builtin_amdgcn_mfma_f32_16x16x32_bf16(fa, fb, a1[i], 0, 0, 0);
          }
        }
      }
      // zero ph pad cols 608..647 and xin
      for (int i = tid; i < 320; i += 256) {
        int r = i / 20, c = i - r * 20;
        *(u32*)&ph[r * 648 + 608 + 2 * c] = 0;
      }
      if (head && donext)
        for (int i = tid; i < 576; i += 256) ((u32*)xin)[i] = 0;
      // ph epilogue: elu(+bias +QE) -> LDS bf16
#pragma unroll
      for (int i = 0; i < 10; i++) {
        int j = w + i * 4;
        if (j >= 38) break;
        int n = j * 16 + r16;
#pragma unroll
        for (int r = 0; r < 4; r++) {
          int mrow = k8g * 4 + r, m = Bm0 + mrow;
          float v = a1[i][r];
          if (n < DET) {
            v += b1[n];
            if (head) v += bf2f(p.QE[((size_t)t * NB + m) * NP + n]);
            ph[mrow * 648 + n] = f2bf(eluf(v));
          } else {
            ph[mrow * 648 + n] = 0;
          }
        }
      }
      __syncthreads();
      // ---- heads2: K=640 split over 4 waves (160 each), LDS reduce
      f32x4 a2[4] = {};
      {
        int kc0 = w * 160;
#pragma unroll
        for (int ks = 0; ks < 5; ks++) {
          int kc = kc0 + ks * 32;
          bf16x8 fa = *(const bf16x8*)&ph[r16 * 648 + kc + k8g * 8];
#pragma unroll
          for (int j = 0; j < 4; j++) {
            bf16x8 fb = *(const bf16x8*)&W2[(size_t)(j * 16 + r16) * NP + kc + k8g * 8];
            a2[j] = __builtin_amdgcn_mfma_f32_16x16x32_bf16(fa, fb, a2[j], 0, 0, 0);
          }
        }
      }
      if (w) {
#pragma unroll
        for (int j = 0; j < 4; j++)
#pragma unroll
          for (int r = 0; r < 4; r++)
            red[(w - 1) * 1024 + (j * 16 + r16) * 16 + k8g * 4 + r] = a2[j][r];
      }
      __syncthreads();
      if (w == 0) {
#pragma unroll
        for (int j = 0; j < 4; j++)
#pragma unroll
          for (int r = 0; r < 4; r++) {
            int c = j * 16 + r16, mr = k8g * 4 + r;
            a2[j][r] += red[c * 16 + mr] + red[1024 + c * 16 + mr] + red[2048 + c * 16 + mr];
          }
        const int ob = head ? 696 : 600;
        const float* ntn = donext ? p.nonterm + (size_t)(t + 1) * NB : nullptr;
#pragma unroll
        for (int j = 0; j < 2; j++) {
          int c = j * 16 + r16;
          float bmu = b2[c], bsd = b2[32 + c];
#pragma unroll
          for (int r = 0; r < 4; r++) {
            int mr = k8g * 4 + r, m = Bm0 + mr;
            float mu = a2[j][r] + bmu;
            float sd = softplusf(a2[j + 2][r] + bsd) + 0.1f;
            float st = mu + sd * noise[(size_t)m * 32 + c];
            float* op = out_t + (size_t)m * OUTW + ob;
            op[c] = mu; op[32 + c] = sd; op[64 + c] = st;
            if (head && donext) xin[mr * 72 + c] = f2bf(st * ntn[m]);
          }
        }
      } else if (w == 1 && head && donext) {
        const float* an = p.actions + (size_t)(t + 1) * NB * 6;
#pragma unroll
        for (int rep = 0; rep < 2; rep++) {
          int idx = lane + rep * 64;
          if (idx < 96) {
            int rr = idx / 6, c = idx - rr * 6;
            xin[rr * 72 + 32 + c] = f2bf(an[(size_t)(Bm0 + rr) * 6 + c]);
          }
        }
      }
      if (head && donext) {
        __syncthreads();
        // xnext: [16][640] = elu(xin[16][64] @ Winp^T + b_in) -> xb
        f32x4 xc[10] = {};
        const int nb = w * 160;
#pragma unroll
        for (int kc = 0; kc < 64; kc += 32) {
          bf16x8 fa = *(const bf16x8*)&xin[r16 * 72 + kc + k8g * 8];
#pragma unroll
          for (int j = 0; j < 10; j++) {
            bf16x8 fb = *(const bf16x8*)&p.Winp[(size_t)(nb + j * 16 + r16) * 64 + kc + k8g * 8];
            xc[j] = __builtin_amdgcn_mfma_f32_16x16x32_bf16(fa, fb, xc[j], 0, 0, 0);
          }
        }
#pragma unroll
        for (int j = 0; j < 10; j++) {
          int n = nb + j * 16 + r16;
          if (n >= DP) continue;
#pragma unroll
          for (int r = 0; r < 4; r++) {
            int m = Bm0 + k8g * 4 + r;
            float v = (n < DET) ? eluf(xc[j][r] + p.b_in[n]) : 0.f;
            p.xb[(size_t)m * DP + n] = f2bf(v);
          }
        }
      }
    }
    gridbar(p.bar, 2 * t + 2);
  }
}

// ---------------- prolog GEMM (QE, x0) ---------------------------------------
struct GemmZ {
  const u16* A; int lda;
  const u16* B; int ldb;
  int K;
  const float* bias;
  u16* C; int ldc;
  int mode;   // 1: elu(x+bias[n<DET]) -> bf16, store n<DP ; 2: raw bf16, store n<ldc
};

__global__ __launch_bounds__(256, 2) void gemmP(GemmZ g)
{
  __shared__ u16 lA[2][128 * 32];
  __shared__ u16 lB[2][128 * 32];
  const int tid = threadIdx.x, lane = tid & 63, w = tid >> 6;
  const int wr = w >> 1, wc = w & 1;
  const size_t m0 = (size_t)blockIdx.y * 128;
  const int n0 = blockIdx.x * 128;
  const int r16 = lane & 15, k8g = lane >> 4;
  f32x4 acc[4][4] = {};

  const int S0 = tid, S1 = tid + 256;
  const int ar0 = S0 >> 2, ak0 = (((S0 & 3) - ((S0 >> 3) & 3)) & 3) * 8;
  const int ar1 = S1 >> 2, ak1 = (((S1 & 3) - ((S1 >> 3) & 3)) & 3) * 8;
  const int lo = w * 1024;
  const int niter = g.K / 32;

  auto stage = [&](int buf, int kc) {
    gll16(g.A + (m0 + ar0) * (size_t)g.lda + kc + ak0, (char*)lA[buf] + lo);
    gll16(g.A + (m0 + ar1) * (size_t)g.lda + kc + ak1, (char*)lA[buf] + 4096 + lo);
    gll16(g.B + (size_t)(n0 + ar0) * g.ldb + kc + ak0, (char*)lB[buf] + lo);
    gll16(g.B + (size_t)(n0 + ar1) * g.ldb + kc + ak1, (char*)lB[buf] + 4096 + lo);
  };
  auto compute = [&](int buf) {
    bf16x8 fa[4], fb[4];
#pragma unroll
    for (int i = 0; i < 4; i++) {
      int row = wr * 64 + i * 16 + r16;
      int S = row * 4 + ((k8g + (row >> 1)) & 3);
      fa[i] = *(const bf16x8*)((const char*)lA[buf] + S * 16);
    }
#pragma unroll
    for (int j = 0; j < 4; j++) {
      int row = wc * 64 + j * 16 + r16;
      int S = row * 4 + ((k8g + (row >> 1)) & 3);
      fb[j] = *(const bf16x8*)((const char*)lB[buf] + S * 16);
    }
#pragma unroll
    for (int i = 0; i < 4; i++)
#pragma unroll
      for (int j = 0; j < 4; j++)
        acc[i][j] = __builtin_amdgcn_mfma_f32_16x16x32_bf16(fa[i], fb[j], acc[i][j], 0, 0, 0);
  };

  stage(0, 0);
  __syncthreads();
  for (int it = 0; it < niter; ++it) {
    if (it + 1 < niter) stage((it + 1) & 1, (it + 1) * 32);
    compute(it & 1);
    __syncthreads();
  }

#pragma unroll
  for (int i = 0; i < 4; i++) {
    size_t mb = m0 + wr * 64 + i * 16 + k8g * 4;
#pragma unroll
    for (int j = 0; j < 4; j++) {
      int n = n0 + wc * 64 + j * 16 + r16;
      if (g.mode == 1) {
        if (n >= DP) continue;
        float b = (n < DET) ? g.bias[n] : 0.f;
#pragma unroll
        for (int r = 0; r < 4; r++)
          g.C[(mb + r) * (size_t)g.ldc + n] = f2bf(eluf(acc[i][j][r] + b));
      } else {
        if (n >= g.ldc) continue;
#pragma unroll
        for (int r = 0; r < 4; r++)
          g.C[(mb + r) * (size_t)g.ldc + n] = f2bf(acc[i][j][r]);
      }
    }
  }
}

// ---------------- small prolog kernels ---------------------------------------
__global__ void wconv_k(const float* src, int srows, int scols, int sstride,
                        u16* dst, int drows, int dstride, int c0, int cw)
{
  int idx = blockIdx.x * 256 + threadIdx.x;
  if (idx >= drows * cw) return;
  int r = idx / cw, c = idx - r * cw;
  float v = (r < srows && c < scols) ? src[(size_t)r * sstride + c] : 0.f;
  dst[(size_t)r * dstride + c0 + c] = f2bf(v);
}

__global__ void conv8_k(const float* src, u16* dst, int n8)
{
  int i = blockIdx.x * 256 + threadIdx.x;
  if (i >= n8) return;
  const float4* s = (const float4*)(src + (size_t)i * 8);
  float4 f0 = s[0], f1 = s[1];
  union { u16 h[8]; int4 v; } cv;
  cv.h[0] = f2bf(f0.x); cv.h[1] = f2bf(f0.y); cv.h[2] = f2bf(f0.z); cv.h[3] = f2bf(f0.w);
  cv.h[4] = f2bf(f1.x); cv.h[5] = f2bf(f1.y); cv.h[6] = f2bf(f1.z); cv.h[7] = f2bf(f1.w);
  *(int4*)(dst + (size_t)i * 8) = cv.v;
}

__global__ void xin0_k(const float* stoc0, const float* nt0, const float* act0, u16* xing)
{
  int i = blockIdx.x * 256 + threadIdx.x;
  if (i >= NB * 64) return;
  int m = i >> 6, c = i & 63;
  float v = 0.f;
  if (c < 32) v = stoc0[m * 32 + c] * nt0[m];
  else if (c < 38) v = act0[m * 6 + (c - 32)];
  xing[i] = f2bf(v);
}

// ---------------- host --------------------------------------------------------
extern "C" void kernel_launch(void* const* d_in, const int* in_sizes, int n_in,
                              void* d_out, int out_size, void* d_ws, size_t ws_size,
                              hipStream_t stream)
{
  const float* actions    = (const float*)d_in[0];
  const float* nonterm    = (const float*)d_in[1];
  const float* emb        = (const float*)d_in[2];
  const float* noise_p    = (const float*)d_in[3];
  const float* noise_q    = (const float*)d_in[4];
  const float* init_deter = (const float*)d_in[5];
  const float* init_stoc  = (const float*)d_in[6];
  const float* W_in = (const float*)d_in[7];
  const float* b_in = (const float*)d_in[8];
  const float* W_ih = (const float*)d_in[9];
  const float* b_ih = (const float*)d_in[10];
  const float* W_hh = (const float*)d_in[11];
  const float* b_hh = (const float*)d_in[12];
  const float* Wp1 = (const float*)d_in[13];
  const float* bp1 = (const float*)d_in[14];
  const float* Wp2 = (const float*)d_in[15];
  const float* bp2 = (const float*)d_in[16];
  const float* Wq1 = (const float*)d_in[17];
  const float* bq1 = (const float*)d_in[18];
  const float* Wq2 = (const float*)d_in[19];
  const float* bq2 = (const float*)d_in[20];
  float* out = (float*)d_out;

  char* wsp = (char*)d_ws;
  size_t o = 0;
  auto alloc = [&](size_t b) { char* pp = wsp + o; o = (o + b + 255) & ~(size_t)255; return pp; };
  u16* W6   = (u16*)alloc(6ull * NP * DP * 2);
  u16* Wp1p = (u16*)alloc((size_t)NP * DP * 2);
  u16* Wq1h = (u16*)alloc((size_t)NP * DP * 2);
  u16* Wq1e = (u16*)alloc((size_t)NP * EMB * 2);
  u16* Wp2p = (u16*)alloc(64ull * NP * 2);
  u16* Wq2p = (u16*)alloc(64ull * NP * 2);
  u16* Winp = (u16*)alloc((size_t)NP * 64 * 2);
  u16* xb   = (u16*)alloc((size_t)NB * DP * 2);
  u16* hb0  = (u16*)alloc((size_t)NB * DP * 2);
  u16* hb1  = (u16*)alloc((size_t)NB * DP * 2);
  u16* xing = (u16*)alloc((size_t)NB * 64 * 2);
  u32* barp = (u32*)alloc(256);
  u16* embb = (u16*)alloc((size_t)NT * NB * EMB * 2);
  u16* QE   = (u16*)alloc((size_t)NT * NB * NP * 2);
  if (o > ws_size) return;  // ws ≈ 800MB observed (R3 fill profile); need ~181MB

  hipMemsetAsync(barp, 0, 256, stream);  // re-init barrier state every call

  auto wcl = [&](const float* src, int sr, int sc, int ss, u16* dst, int dr, int ds, int c0, int cw) {
    int n = dr * cw;
    wconv_k<<<(n + 255) / 256, 256, 0, stream>>>(src, sr, sc, ss, dst, dr, ds, c0, cw);
  };
  for (int s = 0; s < 3; s++) {
    wcl(W_ih + (size_t)s * 600 * 600, 600, 600, 600, W6 + (size_t)s * NP * DP, NP, DP, 0, DP);
    wcl(W_hh + (size_t)s * 600 * 600, 600, 600, 600, W6 + (size_t)(3 + s) * NP * DP, NP, DP, 0, DP);
  }
  wcl(Wp1, 600, 600, 600, Wp1p, NP, DP, 0, DP);
  wcl(Wq1, 600, 600, 1624, Wq1h, NP, DP, 0, DP);
  wcl(Wq1 + 600, 600, 1024, 1624, Wq1e, NP, EMB, 0, EMB);
  wcl(Wp2, 64, 600, 600, Wp2p, 64, NP, 0, NP);     // [64][640], K-padded zeros
  wcl(Wq2, 64, 600, 600, Wq2p, 64, NP, 0, NP);
  wcl(W_in, 600, 38, 38, Winp, NP, 64, 0, 64);
  wcl(init_deter, 1024, 600, 600, hb0, 1024, DP, 0, DP);

  // QE = emb @ Wq1e^T for all T (h-independent, off critical path)
  {
    int n8 = NT * NB * EMB / 8;
    conv8_k<<<(n8 + 255) / 256, 256, 0, stream>>>(emb, embb, n8);
    GemmZ gq = { embb, EMB, Wq1e, EMB, EMB, nullptr, QE, NP, 2 };
    gemmP<<<dim3(5, 400, 1), 256, 0, stream>>>(gq);
  }
  // x_0
  xin0_k<<<NB * 64 / 256, 256, 0, stream>>>(init_stoc, nonterm, actions, xing);
  {
    GemmZ gx = { xing, 64, Winp, 64, 64, b_in, xb, DP, 1 };
    gemmP<<<dim3(5, 8, 1), 256, 0, stream>>>(gx);
  }

  // persistent rollout (plain launch + manual grid barrier; 160 blocks x 64KB LDS
  // -> 2 blocks/CU capacity on 256 CUs, stream empty => all co-resident)
  PK pk = { W6, Wp1p, Wq1h, Wp2p, Wq2p, Winp, QE,
            b_ih, b_hh, bp1, bq1, bp2, bq2, b_in,
            init_deter, actions, nonterm, noise_p, noise_q,
            xb, hb0, hb1, out, barp };
  rssm_persist<<<GBLK, 256, 0, stream>>>(pk);
}

// Round 6
// 6691.045 us; speedup vs baseline: 1.2030x; 1.2030x over previous
//
#include <hip/hip_runtime.h>

typedef __bf16 bf16x8 __attribute__((ext_vector_type(8)));
typedef float f32x4 __attribute__((ext_vector_type(4)));
typedef unsigned short u16;
typedef unsigned int u32;
typedef unsigned long long u64;

#define NT 50
#define NB 1024
#define DET 600
#define DP 608        // padded 600 -> 19*32
#define NP 640        // padded 600 -> 5*128
#define EMB 1024
#define OUTW 792
#define GBLK 160      // persistent grid: phase A=160 tiles, phase B=128 slices
#define SUBN 8
#define BPS (GBLK / SUBN)   // blocks per sub-barrier = 20

__device__ __forceinline__ u16 f2bf(float f) {
  unsigned u = __float_as_uint(f);
  u += 0x7FFFu + ((u >> 16) & 1u);
  return (u16)(u >> 16);
}
__device__ __forceinline__ float bf2f(u16 h) { return __uint_as_float(((unsigned)h) << 16); }
__device__ __forceinline__ float eluf(float x) { return x > 0.f ? x : expm1f(x); }
__device__ __forceinline__ float sigm(float x) { return 1.f / (1.f + expf(-x)); }
__device__ __forceinline__ float softplusf(float x) {
  return fmaxf(x, 0.f) + log1pf(expf(-fabsf(x)));
}

// async global->LDS, 16B/lane. AUX: 0 = cached (read-only data), 17 = SC0|SC1
// (coherent: bypass local L1/L2, read from L3 coherence point).
template<int AUX>
__device__ __forceinline__ void gll16a(const void* g, void* l) {
  __builtin_amdgcn_global_load_lds(
      (const __attribute__((address_space(1))) u32*)g,
      (__attribute__((address_space(3))) u32*)l, 16, 0, AUX);
}

// system-scope relaxed atomics = sc0 sc1 load/store, no fences, no cache inv.
__device__ __forceinline__ u32 ld32sc(const u32* p_) {
  return __hip_atomic_load(p_, __ATOMIC_RELAXED, __HIP_MEMORY_SCOPE_SYSTEM);
}
__device__ __forceinline__ void st32sc(u32* p_, u32 v) {
  __hip_atomic_store(p_, v, __ATOMIC_RELAXED, __HIP_MEMORY_SCOPE_SYSTEM);
}

// Hierarchical grid barrier, monotone targets, all-relaxed (coherence of data
// is carried by the sc0sc1 write-through stores, drained by the vmcnt(0) the
// compiler emits at __syncthreads). No buffer_inv/wbl2 -> L2 stays warm.
__device__ __forceinline__ void gridbar(u32* bar, u32 target) {
  __syncthreads();   // all 4 waves drain their vmem (incl. sc stores) here
  if (threadIdx.x == 0) {
    __builtin_amdgcn_s_waitcnt(0);
    __builtin_amdgcn_sched_barrier(0);
    const int sub = blockIdx.x & 7;
    u32 a = __hip_atomic_fetch_add(&bar[sub * 32], 1u, __ATOMIC_RELAXED,
                                   __HIP_MEMORY_SCOPE_SYSTEM);
    bool done = false;
    if (a == target * BPS - 1) {          // last arriver in sub-group
      u32 r = __hip_atomic_fetch_add(&bar[8 * 32], 1u, __ATOMIC_RELAXED,
                                     __HIP_MEMORY_SCOPE_SYSTEM);
      if (r == target * SUBN - 1) {       // last sub-group -> release flag
        __hip_atomic_store(&bar[9 * 32], target, __ATOMIC_RELAXED,
                           __HIP_MEMORY_SCOPE_SYSTEM);
        done = true;
      }
    }
    if (!done) {
      while (__hip_atomic_load(&bar[9 * 32], __ATOMIC_RELAXED,
                               __HIP_MEMORY_SCOPE_SYSTEM) < target)
        __builtin_amdgcn_s_sleep(4);
    }
    __builtin_amdgcn_sched_barrier(0);
  }
  __syncthreads();
}

// Swizzled chunk layout for [rows][32] bf16 tiles staged as 16B chunks:
// chunk S holds (row = S>>2, k8 = ((S&3) - ((S>>3)&3)) & 3).
// reader for (row,k8): S = row*4 + ((k8 + (row>>1)) & 3)  -> 2-way banks (free).

struct PK {
  const u16 *W6, *Wp1, *Wq1h, *Wp2, *Wq2, *Winp, *QE;
  const float *b_ih, *b_hh, *bp1, *bq1, *bp2, *bq2, *b_in;
  const float *init_deter, *actions, *nonterm, *noise_p, *noise_q;
  u16 *xb, *hb0, *hb1;
  float *out;
  u32 *bar;
};

__global__ __launch_bounds__(256, 1) void rssm_persist(PK p)
{
  __shared__ char smem[65536] __attribute__((aligned(16)));

  const int bid = blockIdx.x, tid = threadIdx.x;
  const int lane = tid & 63, w = tid >> 6;
  const int r16 = lane & 15, k8g = lane >> 4;

  // ----- phase A config (GRU 64x64x6 tile). nx -> XCD affinity (XCD=bid%8).
  int my, nx;
  if (bid < 128) { my = bid >> 3; nx = bid & 7; }
  else           { my = (bid - 128) >> 1; nx = 8 + (bid & 1); }
  const int Am0 = my * 64, An0 = nx * 64;
  const int wr = w >> 1, wc = w & 1;
  const int srow = tid >> 2;
  const int sk8 = ((tid & 3) - ((tid >> 3) & 3)) & 3;
  const int lo = w * 1024;
  const u16* bw[6];
#pragma unroll
  for (int s = 0; s < 6; s++)
    bw[s] = p.W6 + (size_t)s * NP * DP + (size_t)(An0 + srow) * DP + sk8 * 8;
  const size_t aoff = (size_t)(Am0 + srow) * DP + sk8 * 8;

  // ----- phase B config (heads for 16-row slice x head), bid 0..127
  const bool doB = bid < 128;
  const int slice = bid >> 1, head = bid & 1;
  const int Bm0 = slice * 16;
  const u16* W1 = head ? p.Wq1h : p.Wp1;
  const float* b1 = head ? p.bq1 : p.bp1;
  const u16* W2 = head ? p.Wq2 : p.Wp2;
  const float* b2 = head ? p.bq2 : p.bp2;

  // phase-B LDS layout (reuses phase-A staging area; phases barrier-separated)
  u16* hsl = (u16*)smem;                     // [16][616] bf16 (pad cols 608..615)
  u16* ph  = (u16*)(smem + 19712);           // [16][648] bf16 (cols 600..647 zero)
  float* red = (float*)(smem + 40448);       // [3][64][16] f32
  u16* xin = (u16*)(smem + 52736);           // [16][72] bf16

  for (int t = 0; t < NT; ++t) {
    const u16* hcur = (t & 1) ? p.hb1 : p.hb0;
    u16* hnxt = (t & 1) ? p.hb0 : p.hb1;
    float* out_t = p.out + (size_t)t * NB * OUTW;

    // =================== phase A: GRU ===================
    {
      const u16* axp = p.xb + aoff;
      const u16* ahp = hcur + aoff;
      auto ldsT = [&](int buf, int tile) -> char* { return smem + buf * 32768 + tile * 4096; };
      f32x4 acc[6][2][2] = {};
      auto stage = [&](int buf, int kc) {
        gll16a<17>(axp + kc, ldsT(buf, 0) + lo);   // x, h: mutable -> SC
        gll16a<17>(ahp + kc, ldsT(buf, 1) + lo);
#pragma unroll
        for (int s = 0; s < 6; s++) gll16a<0>(bw[s] + kc, ldsT(buf, 2 + s) + lo);
      };
      auto compute = [&](int buf) {
        bf16x8 ax_[2], ah_[2];
#pragma unroll
        for (int i = 0; i < 2; i++) {
          int row = wr * 32 + i * 16 + r16;
          int S = row * 4 + ((k8g + (row >> 1)) & 3);
          ax_[i] = *(const bf16x8*)(ldsT(buf, 0) + S * 16);
          ah_[i] = *(const bf16x8*)(ldsT(buf, 1) + S * 16);
        }
#pragma unroll
        for (int s = 0; s < 6; s++) {
#pragma unroll
          for (int j = 0; j < 2; j++) {
            int row = wc * 32 + j * 16 + r16;
            int S = row * 4 + ((k8g + (row >> 1)) & 3);
            bf16x8 b = *(const bf16x8*)(ldsT(buf, 2 + s) + S * 16);
#pragma unroll
            for (int i = 0; i < 2; i++)
              acc[s][i][j] = __builtin_amdgcn_mfma_f32_16x16x32_bf16(
                  (s < 3) ? ax_[i] : ah_[i], b, acc[s][i][j], 0, 0, 0);
          }
        }
      };
      stage(0, 0);
      __syncthreads();
      for (int it = 0; it < 19; ++it) {
        if (it + 1 < 19) stage((it + 1) & 1, (it + 1) * 32);
        compute(it & 1);
        __syncthreads();
      }
      const float* dprev = t ? (out_t - (size_t)NB * OUTW) : p.init_deter;
      const int dstr = t ? OUTW : DET;
#pragma unroll
      for (int j = 0; j < 2; j++) {
        int n = An0 + wc * 32 + j * 16 + r16;
        bool nok = (n < DET);   // pads of hnxt pre-zeroed once; never written here
        float bihr = nok ? p.b_ih[n] : 0.f, bhhr = nok ? p.b_hh[n] : 0.f;
        float bihz = nok ? p.b_ih[600 + n] : 0.f, bhhz = nok ? p.b_hh[600 + n] : 0.f;
        float bihn = nok ? p.b_ih[1200 + n] : 0.f, bhhn = nok ? p.b_hh[1200 + n] : 0.f;
#pragma unroll
        for (int i = 0; i < 2; i++) {
          int mb = Am0 + wr * 32 + i * 16 + k8g * 4;
#pragma unroll
          for (int r = 0; r < 4; r++) {
            int m = mb + r;
            float dp = nok ? __uint_as_float(ld32sc((const u32*)&dprev[(size_t)m * dstr + n])) : 0.f;
            float rg = sigm(acc[0][i][j][r] + bihr + acc[3][i][j][r] + bhhr);
            float zg = sigm(acc[1][i][j][r] + bihz + acc[4][i][j][r] + bhhz);
            float ng = tanhf(acc[2][i][j][r] + bihn + rg * (acc[5][i][j][r] + bhhn));
            float h = (1.f - zg) * ng + zg * dp;
            u32 hb16 = f2bf(h);
            u32 other = (u32)__shfl_xor((int)hb16, 1, 64);  // partner has n^1
            if (nok) {
              st32sc((u32*)&out_t[(size_t)m * OUTW + n], __float_as_uint(h));
              if (!(lane & 1))   // n even; pair (n,n+1) both < 600 (600 even)
                st32sc((u32*)&hnxt[(size_t)m * DP + n], hb16 | (other << 16));
            }
          }
        }
      }
    }
    gridbar(p.bar, 2 * t + 1);

    // =================== phase B: heads + sampling + xnext ===================
    if (doB) {
      const bool donext = (t + 1 < NT);
      const float* noise = (head ? p.noise_q : p.noise_p) + (size_t)t * NB * 32;

      // stage h slice [16][608] -> hsl [16][616] via SC loads (one shot).
      // 1232 16B-chunks, row = chunk/77 (77th chunk per row fills pad, clamped src)
      {
        const u16* hrow = hnxt + (size_t)Bm0 * DP;
#pragma unroll
        for (int c = 0; c < 5; ++c) {
          int chunk = c * 256 + tid;
          char* ldst = (char*)hsl + (c * 256 + w * 64) * 16;  // wave-uniform base
          if (chunk < 1232) {
            int row = chunk / 77, cc = chunk - row * 77;
            int scc = cc < 76 ? cc : 75;
            gll16a<17>(hrow + (size_t)row * DP + scc * 8, ldst);
          }
        }
      }
      // zero ph pad cols 608..647 and xin
      for (int i = tid; i < 320; i += 256) {
        int r = i / 20, c = i - r * 20;
        *(u32*)&ph[r * 648 + 608 + 2 * c] = 0;
      }
      if (donext)
        for (int i = tid; i < 576; i += 256) ((u32*)xin)[i] = 0;
      __syncthreads();

      // ---- heads1: [16 rows] x [608 cols], K=608; A from LDS, W1 from L2
      f32x4 a1[10] = {};
      for (int kc = 0; kc < DP; kc += 32) {
        bf16x8 fa = *(const bf16x8*)&hsl[r16 * 616 + kc + k8g * 8];
#pragma unroll
        for (int i = 0; i < 10; i++) {
          int j = w + i * 4;
          if (j < 38) {
            bf16x8 fb = *(const bf16x8*)&W1[(size_t)(j * 16 + r16) * DP + kc + k8g * 8];
            a1[i] = __builtin_amdgcn_mfma_f32_16x16x32_bf16(fa, fb, a1[i], 0, 0, 0);
          }
        }
      }
      // ph epilogue: elu(+bias +QE) -> LDS bf16
#pragma unroll
      for (int i = 0; i < 10; i++) {
        int j = w + i * 4;
        if (j >= 38) break;
        int n = j * 16 + r16;
#pragma unroll
        for (int r = 0; r < 4; r++) {
          int mrow = k8g * 4 + r, m = Bm0 + mrow;
          float v = a1[i][r];
          if (n < DET) {
            v += b1[n];
            if (head) v += bf2f(p.QE[((size_t)t * NB + m) * NP + n]);
            ph[mrow * 648 + n] = f2bf(eluf(v));
          } else {
            ph[mrow * 648 + n] = 0;
          }
        }
      }
      __syncthreads();
      // ---- heads2: K=640 split over 4 waves (160 each), LDS reduce
      f32x4 a2[4] = {};
      {
        int kc0 = w * 160;
#pragma unroll
        for (int ks = 0; ks < 5; ks++) {
          int kc = kc0 + ks * 32;
          bf16x8 fa = *(const bf16x8*)&ph[r16 * 648 + kc + k8g * 8];
#pragma unroll
          for (int j = 0; j < 4; j++) {
            bf16x8 fb = *(const bf16x8*)&W2[(size_t)(j * 16 + r16) * NP + kc + k8g * 8];
            a2[j] = __builtin_amdgcn_mfma_f32_16x16x32_bf16(fa, fb, a2[j], 0, 0, 0);
          }
        }
      }
      if (w) {
#pragma unroll
        for (int j = 0; j < 4; j++)
#pragma unroll
          for (int r = 0; r < 4; r++)
            red[(w - 1) * 1024 + (j * 16 + r16) * 16 + k8g * 4 + r] = a2[j][r];
      }
      __syncthreads();
      if (w == 0) {
#pragma unroll
        for (int j = 0; j < 4; j++)
#pragma unroll
          for (int r = 0; r < 4; r++) {
            int c = j * 16 + r16, mr = k8g * 4 + r;
            a2[j][r] += red[c * 16 + mr] + red[1024 + c * 16 + mr] + red[2048 + c * 16 + mr];
          }
        const int ob = head ? 696 : 600;
        const float* ntn = donext ? p.nonterm + (size_t)(t + 1) * NB : nullptr;
#pragma unroll
        for (int j = 0; j < 2; j++) {
          int c = j * 16 + r16;
          float bmu = b2[c], bsd = b2[32 + c];
#pragma unroll
          for (int r = 0; r < 4; r++) {
            int mr = k8g * 4 + r, m = Bm0 + mr;
            float mu = a2[j][r] + bmu;
            float sd = softplusf(a2[j + 2][r] + bsd) + 0.1f;
            float st = mu + sd * noise[(size_t)m * 32 + c];
            float* op = out_t + (size_t)m * OUTW + ob;
            op[c] = mu; op[32 + c] = sd; op[64 + c] = st;   // host-only: plain
            if (head && donext) xin[mr * 72 + c] = f2bf(st * ntn[m]);
          }
        }
      } else if (w == 1 && head && donext) {
        const float* an = p.actions + (size_t)(t + 1) * NB * 6;
#pragma unroll
        for (int rep = 0; rep < 2; rep++) {
          int idx = lane + rep * 64;
          if (idx < 96) {
            int rr = idx / 6, c = idx - rr * 6;
            xin[rr * 72 + 32 + c] = f2bf(an[(size_t)(Bm0 + rr) * 6 + c]);
          }
        }
      }
      if (head && donext) {
        __syncthreads();
        // xnext: [16][600] = elu(xin[16][64] @ Winp^T + b_in) -> xb (SC, packed)
        f32x4 xc[10] = {};
        const int nb = w * 160;
#pragma unroll
        for (int kc = 0; kc < 64; kc += 32) {
          bf16x8 fa = *(const bf16x8*)&xin[r16 * 72 + kc + k8g * 8];
#pragma unroll
          for (int j = 0; j < 10; j++) {
            bf16x8 fb = *(const bf16x8*)&p.Winp[(size_t)(nb + j * 16 + r16) * 64 + kc + k8g * 8];
            xc[j] = __builtin_amdgcn_mfma_f32_16x16x32_bf16(fa, fb, xc[j], 0, 0, 0);
          }
        }
#pragma unroll
        for (int j = 0; j < 10; j++) {
          int n = nb + j * 16 + r16;
          bool nok = (n < DET);
          float bi = nok ? p.b_in[n] : 0.f;
#pragma unroll
          for (int r = 0; r < 4; r++) {
            int m = Bm0 + k8g * 4 + r;
            float v = eluf(xc[j][r] + bi);
            u32 xb16 = f2bf(v);
            u32 other = (u32)__shfl_xor((int)xb16, 1, 64);
            if (nok && !(lane & 1))
              st32sc((u32*)&p.xb[(size_t)m * DP + n], xb16 | (other << 16));
          }
        }
      }
    }
    if (t + 1 < NT) gridbar(p.bar, 2 * t + 2);
  }
}

// ---------------- prolog GEMM (QE, x0) ---------------------------------------
struct GemmZ {
  const u16* A; int lda;
  const u16* B; int ldb;
  int K;
  const float* bias;
  u16* C; int ldc;
  int mode;   // 1: elu(x+bias[n<DET]) -> bf16, store n<DP ; 2: raw bf16, store n<ldc
};

__global__ __launch_bounds__(256, 2) void gemmP(GemmZ g)
{
  __shared__ u16 lA[2][128 * 32];
  __shared__ u16 lB[2][128 * 32];
  const int tid = threadIdx.x, lane = tid & 63, w = tid >> 6;
  const int wr = w >> 1, wc = w & 1;
  const size_t m0 = (size_t)blockIdx.y * 128;
  const int n0 = blockIdx.x * 128;
  const int r16 = lane & 15, k8g = lane >> 4;
  f32x4 acc[4][4] = {};

  const int S0 = tid, S1 = tid + 256;
  const int ar0 = S0 >> 2, ak0 = (((S0 & 3) - ((S0 >> 3) & 3)) & 3) * 8;
  const int ar1 = S1 >> 2, ak1 = (((S1 & 3) - ((S1 >> 3) & 3)) & 3) * 8;
  const int lo = w * 1024;
  const int niter = g.K / 32;

  auto stage = [&](int buf, int kc) {
    gll16a<0>(g.A + (m0 + ar0) * (size_t)g.lda + kc + ak0, (char*)lA[buf] + lo);
    gll16a<0>(g.A + (m0 + ar1) * (size_t)g.lda + kc + ak1, (char*)lA[buf] + 4096 + lo);
    gll16a<0>(g.B + (size_t)(n0 + ar0) * g.ldb + kc + ak0, (char*)lB[buf] + lo);
    gll16a<0>(g.B + (size_t)(n0 + ar1) * g.ldb + kc + ak1, (char*)lB[buf] + 4096 + lo);
  };
  auto compute = [&](int buf) {
    bf16x8 fa[4], fb[4];
#pragma unroll
    for (int i = 0; i < 4; i++) {
      int row = wr * 64 + i * 16 + r16;
      int S = row * 4 + ((k8g + (row >> 1)) & 3);
      fa[i] = *(const bf16x8*)((const char*)lA[buf] + S * 16);
    }
#pragma unroll
    for (int j = 0; j < 4; j++) {
      int row = wc * 64 + j * 16 + r16;
      int S = row * 4 + ((k8g + (row >> 1)) & 3);
      fb[j] = *(const bf16x8*)((const char*)lB[buf] + S * 16);
    }
#pragma unroll
    for (int i = 0; i < 4; i++)
#pragma unroll
      for (int j = 0; j < 4; j++)
        acc[i][j] = __builtin_amdgcn_mfma_f32_16x16x32_bf16(fa[i], fb[j], acc[i][j], 0, 0, 0);
  };

  stage(0, 0);
  __syncthreads();
  for (int it = 0; it < niter; ++it) {
    if (it + 1 < niter) stage((it + 1) & 1, (it + 1) * 32);
    compute(it & 1);
    __syncthreads();
  }

#pragma unroll
  for (int i = 0; i < 4; i++) {
    size_t mb = m0 + wr * 64 + i * 16 + k8g * 4;
#pragma unroll
    for (int j = 0; j < 4; j++) {
      int n = n0 + wc * 64 + j * 16 + r16;
      if (g.mode == 1) {
        if (n >= DP) continue;
        float b = (n < DET) ? g.bias[n] : 0.f;
#pragma unroll
        for (int r = 0; r < 4; r++)
          g.C[(mb + r) * (size_t)g.ldc + n] = f2bf(eluf(acc[i][j][r] + b));
      } else {
        if (n >= g.ldc) continue;
#pragma unroll
        for (int r = 0; r < 4; r++)
          g.C[(mb + r) * (size_t)g.ldc + n] = f2bf(acc[i][j][r]);
      }
    }
  }
}

// ---------------- small prolog kernels ---------------------------------------
__global__ void wconv_k(const float* src, int srows, int scols, int sstride,
                        u16* dst, int drows, int dstride, int c0, int cw)
{
  int idx = blockIdx.x * 256 + threadIdx.x;
  if (idx >= drows * cw) return;
  int r = idx / cw, c = idx - r * cw;
  float v = (r < srows && c < scols) ? src[(size_t)r * sstride + c] : 0.f;
  dst[(size_t)r * dstride + c0 + c] = f2bf(v);
}

__global__ void conv8_k(const float* src, u16* dst, int n8)
{
  int i = blockIdx.x * 256 + threadIdx.x;
  if (i >= n8) return;
  const float4* s = (const float4*)(src + (size_t)i * 8);
  float4 f0 = s[0], f1 = s[1];
  union { u16 h[8]; int4 v; } cv;
  cv.h[0] = f2bf(f0.x); cv.h[1] = f2bf(f0.y); cv.h[2] = f2bf(f0.z); cv.h[3] = f2bf(f0.w);
  cv.h[4] = f2bf(f1.x); cv.h[5] = f2bf(f1.y); cv.h[6] = f2bf(f1.z); cv.h[7] = f2bf(f1.w);
  *(int4*)(dst + (size_t)i * 8) = cv.v;
}

__global__ void xin0_k(const float* stoc0, const float* nt0, const float* act0, u16* xing)
{
  int i = blockIdx.x * 256 + threadIdx.x;
  if (i >= NB * 64) return;
  int m = i >> 6, c = i & 63;
  float v = 0.f;
  if (c < 32) v = stoc0[m * 32 + c] * nt0[m];
  else if (c < 38) v = act0[m * 6 + (c - 32)];
  xing[i] = f2bf(v);
}

// ---------------- host --------------------------------------------------------
extern "C" void kernel_launch(void* const* d_in, const int* in_sizes, int n_in,
                              void* d_out, int out_size, void* d_ws, size_t ws_size,
                              hipStream_t stream)
{
  const float* actions    = (const float*)d_in[0];
  const float* nonterm    = (const float*)d_in[1];
  const float* emb        = (const float*)d_in[2];
  const float* noise_p    = (const float*)d_in[3];
  const float* noise_q    = (const float*)d_in[4];
  const float* init_deter = (const float*)d_in[5];
  const float* init_stoc  = (const float*)d_in[6];
  const float* W_in = (const float*)d_in[7];
  const float* b_in = (const float*)d_in[8];
  const float* W_ih = (const float*)d_in[9];
  const float* b_ih = (const float*)d_in[10];
  const float* W_hh = (const float*)d_in[11];
  const float* b_hh = (const float*)d_in[12];
  const float* Wp1 = (const float*)d_in[13];
  const float* bp1 = (const float*)d_in[14];
  const float* Wp2 = (const float*)d_in[15];
  const float* bp2 = (const float*)d_in[16];
  const float* Wq1 = (const float*)d_in[17];
  const float* bq1 = (const float*)d_in[18];
  const float* Wq2 = (const float*)d_in[19];
  const float* bq2 = (const float*)d_in[20];
  float* out = (float*)d_out;

  char* wsp = (char*)d_ws;
  size_t o = 0;
  auto alloc = [&](size_t b) { char* pp = wsp + o; o = (o + b + 255) & ~(size_t)255; return pp; };
  u16* W6   = (u16*)alloc(6ull * NP * DP * 2);
  u16* Wp1p = (u16*)alloc((size_t)NP * DP * 2);
  u16* Wq1h = (u16*)alloc((size_t)NP * DP * 2);
  u16* Wq1e = (u16*)alloc((size_t)NP * EMB * 2);
  u16* Wp2p = (u16*)alloc(64ull * NP * 2);
  u16* Wq2p = (u16*)alloc(64ull * NP * 2);
  u16* Winp = (u16*)alloc((size_t)NP * 64 * 2);
  u16* xb   = (u16*)alloc((size_t)NB * DP * 2);
  u16* hb0  = (u16*)alloc((size_t)NB * DP * 2);
  u16* hb1  = (u16*)alloc((size_t)NB * DP * 2);
  u16* xing = (u16*)alloc((size_t)NB * 64 * 2);
  u32* barp = (u32*)alloc(4096);
  u16* embb = (u16*)alloc((size_t)NT * NB * EMB * 2);
  u16* QE   = (u16*)alloc((size_t)NT * NB * NP * 2);
  if (o > ws_size) return;  // need ~181MB; ws observed ~800MB

  hipMemsetAsync(barp, 0, 4096, stream);              // barrier counters
  hipMemsetAsync(hb1, 0, (size_t)NB * DP * 2, stream); // hb1 pads stay 0 forever

  auto wcl = [&](const float* src, int sr, int sc, int ss, u16* dst, int dr, int ds, int c0, int cw) {
    int n = dr * cw;
    wconv_k<<<(n + 255) / 256, 256, 0, stream>>>(src, sr, sc, ss, dst, dr, ds, c0, cw);
  };
  for (int s = 0; s < 3; s++) {
    wcl(W_ih + (size_t)s * 600 * 600, 600, 600, 600, W6 + (size_t)s * NP * DP, NP, DP, 0, DP);
    wcl(W_hh + (size_t)s * 600 * 600, 600, 600, 600, W6 + (size_t)(3 + s) * NP * DP, NP, DP, 0, DP);
  }
  wcl(Wp1, 600, 600, 600, Wp1p, NP, DP, 0, DP);
  wcl(Wq1, 600, 600, 1624, Wq1h, NP, DP, 0, DP);
  wcl(Wq1 + 600, 600, 1024, 1624, Wq1e, NP, EMB, 0, EMB);
  wcl(Wp2, 64, 600, 600, Wp2p, 64, NP, 0, NP);
  wcl(Wq2, 64, 600, 600, Wq2p, 64, NP, 0, NP);
  wcl(W_in, 600, 38, 38, Winp, NP, 64, 0, 64);
  wcl(init_deter, 1024, 600, 600, hb0, 1024, DP, 0, DP);

  // QE = emb @ Wq1e^T for all T (h-independent, off critical path)
  {
    int n8 = NT * NB * EMB / 8;
    conv8_k<<<(n8 + 255) / 256, 256, 0, stream>>>(emb, embb, n8);
    GemmZ gq = { embb, EMB, Wq1e, EMB, EMB, nullptr, QE, NP, 2 };
    gemmP<<<dim3(5, 400, 1), 256, 0, stream>>>(gq);
  }
  // x_0
  xin0_k<<<NB * 64 / 256, 256, 0, stream>>>(init_stoc, nonterm, actions, xing);
  {
    GemmZ gx = { xing, 64, Winp, 64, 64, b_in, xb, DP, 1 };
    gemmP<<<dim3(5, 8, 1), 256, 0, stream>>>(gx);
  }

  // persistent rollout: 160 blocks x 64KB LDS -> co-resident by capacity.
  PK pk = { W6, Wp1p, Wq1h, Wp2p, Wq2p, Winp, QE,
            b_ih, b_hh, bp1, bq1, bp2, bq2, b_in,
            init_deter, actions, nonterm, noise_p, noise_q,
            xb, hb0, hb1, out, barp };
  rssm_persist<<<GBLK, 256, 0, stream>>>(pk);
}

// Round 7
// 6218.531 us; speedup vs baseline: 1.2944x; 1.0760x over previous
//
#include <hip/hip_runtime.h>

typedef __bf16 bf16x8 __attribute__((ext_vector_type(8)));
typedef float f32x4 __attribute__((ext_vector_type(4)));
typedef unsigned short u16;
typedef unsigned int u32;
typedef unsigned long long u64;

#define NT 50
#define NB 1024
#define DET 600
#define DP 608        // padded 600 -> 19*32
#define NP 640        // padded 600 -> 5*128
#define EMB 1024
#define OUTW 792
#define GBLK 160      // persistent grid: phase A=160 tiles, phase B=128 slices
#define SUBN 8
#define BPS (GBLK / SUBN)   // blocks per sub-barrier = 20
#define HXS ((size_t)NB * DP)   // per-step h/x buffer stride (elements)

__device__ __forceinline__ u16 f2bf(float f) {
  unsigned u = __float_as_uint(f);
  u += 0x7FFFu + ((u >> 16) & 1u);
  return (u16)(u >> 16);
}
__device__ __forceinline__ float bf2f(u16 h) { return __uint_as_float(((unsigned)h) << 16); }
__device__ __forceinline__ float eluf(float x) { return x > 0.f ? x : expm1f(x); }
__device__ __forceinline__ float sigm(float x) { return 1.f / (1.f + expf(-x)); }
__device__ __forceinline__ float softplusf(float x) {
  return fmaxf(x, 0.f) + log1pf(expf(-fabsf(x)));
}

// async global->LDS, 16B/lane, normal cached path (weights AND fresh per-step
// buffers -- unique-buffer scheme makes cached reads safe).
__device__ __forceinline__ void gll16(const void* g, void* l) {
  __builtin_amdgcn_global_load_lds(
      (const __attribute__((address_space(1))) u32*)g,
      (__attribute__((address_space(3))) u32*)l, 16, 0, 0);
}

// write-through store (sc0sc1): data reaches the L3 coherence point so other
// XCDs' virgin-line fetches see it. No cache invalidates anywhere.
__device__ __forceinline__ void st32sc(u32* p_, u32 v) {
  __hip_atomic_store(p_, v, __ATOMIC_RELAXED, __HIP_MEMORY_SCOPE_SYSTEM);
}

// Hierarchical grid barrier, monotone targets, all-relaxed.
__device__ __forceinline__ void gridbar(u32* bar, u32 target) {
  __syncthreads();   // all 4 waves drain their vmem here
  if (threadIdx.x == 0) {
    __builtin_amdgcn_s_waitcnt(0);
    __builtin_amdgcn_sched_barrier(0);
    const int sub = blockIdx.x & 7;
    u32 a = __hip_atomic_fetch_add(&bar[sub * 32], 1u, __ATOMIC_RELAXED,
                                   __HIP_MEMORY_SCOPE_SYSTEM);
    bool done = false;
    if (a == target * BPS - 1) {          // last arriver in sub-group
      u32 r = __hip_atomic_fetch_add(&bar[8 * 32], 1u, __ATOMIC_RELAXED,
                                     __HIP_MEMORY_SCOPE_SYSTEM);
      if (r == target * SUBN - 1) {       // last sub-group -> release flag
        __hip_atomic_store(&bar[9 * 32], target, __ATOMIC_RELAXED,
                           __HIP_MEMORY_SCOPE_SYSTEM);
        done = true;
      }
    }
    if (!done) {
      while (__hip_atomic_load(&bar[9 * 32], __ATOMIC_RELAXED,
                               __HIP_MEMORY_SCOPE_SYSTEM) < target)
        __builtin_amdgcn_s_sleep(2);
    }
    __builtin_amdgcn_sched_barrier(0);
  }
  __syncthreads();
}

// Swizzled chunk layout for [rows][32] bf16 tiles staged as 16B chunks:
// chunk S holds (row = S>>2, k8 = ((S&3) - ((S>>3)&3)) & 3).
// reader for (row,k8): S = row*4 + ((k8 + (row>>1)) & 3)  -> 2-way banks (free).

struct PK {
  const u16 *W6, *Wp1, *Wq1h, *Wp2, *Wq2, *Winp, *QE;
  const float *b_ih, *b_hh, *bp1, *bq1, *bp2, *bq2, *b_in;
  const float *init_deter, *actions, *nonterm, *noise_p, *noise_q;
  u16 *xbuf, *hbuf;    // per-step unique buffers: xbuf[t], hbuf[t] (stride HXS)
  float *out;
  u32 *bar;
};

__global__ __launch_bounds__(256, 1) void rssm_persist(PK p)
{
  __shared__ char smem[65536] __attribute__((aligned(16)));

  const int bid = blockIdx.x, tid = threadIdx.x;
  const int lane = tid & 63, w = tid >> 6;
  const int r16 = lane & 15, k8g = lane >> 4;

  // ----- phase A config (GRU 64x64x6 tile). nx -> XCD affinity (XCD=bid%8).
  int my, nx;
  if (bid < 128) { my = bid >> 3; nx = bid & 7; }
  else           { my = (bid - 128) >> 1; nx = 8 + (bid & 1); }
  const int Am0 = my * 64, An0 = nx * 64;
  const int wr = w >> 1, wc = w & 1;
  const int srow = tid >> 2;
  const int sk8 = ((tid & 3) - ((tid >> 3) & 3)) & 3;
  const int lo = w * 1024;
  const u16* bw[6];
#pragma unroll
  for (int s = 0; s < 6; s++)
    bw[s] = p.W6 + (size_t)s * NP * DP + (size_t)(An0 + srow) * DP + sk8 * 8;
  const size_t aoff = (size_t)(Am0 + srow) * DP + sk8 * 8;

  // ----- phase B config (heads for 16-row slice x head), bid 0..127
  const bool doB = bid < 128;
  const int slice = bid >> 1, head = bid & 1;
  const int Bm0 = slice * 16;
  const u16* W1 = head ? p.Wq1h : p.Wp1;
  const float* b1 = head ? p.bq1 : p.bp1;
  const u16* W2 = head ? p.Wq2 : p.Wp2;
  const float* b2 = head ? p.bq2 : p.bp2;

  // phase-B LDS layout (reuses phase-A staging area; phases barrier-separated)
  u16* hsl = (u16*)smem;                     // [16][616] bf16 (pad cols 608..615)
  u16* ph  = (u16*)(smem + 19712);           // [16][648] bf16 (cols 600..647 zero)
  float* red = (float*)(smem + 40448);       // [3][64][16] f32
  u16* xin = (u16*)(smem + 52736);           // [16][72] bf16

  for (int t = 0; t < NT; ++t) {
    const u16* hprev = p.hbuf + (size_t)t * HXS;        // h_{t-1} (bf16)
    u16* hnow = p.hbuf + (size_t)(t + 1) * HXS;         // h_t (written here)
    const u16* xcur = p.xbuf + (size_t)t * HXS;         // x_t
    u16* xnxt = p.xbuf + (size_t)(t + 1) * HXS;         // x_{t+1}
    float* out_t = p.out + (size_t)t * NB * OUTW;

    // =================== phase A: GRU ===================
    {
      const u16* axp = xcur + aoff;
      const u16* ahp = hprev + aoff;
      auto ldsT = [&](int buf, int tile) -> char* { return smem + buf * 32768 + tile * 4096; };
      f32x4 acc[6][2][2] = {};
      auto stage = [&](int buf, int kc) {
        gll16(axp + kc, ldsT(buf, 0) + lo);
        gll16(ahp + kc, ldsT(buf, 1) + lo);
#pragma unroll
        for (int s = 0; s < 6; s++) gll16(bw[s] + kc, ldsT(buf, 2 + s) + lo);
      };
      auto compute = [&](int buf) {
        bf16x8 ax_[2], ah_[2];
#pragma unroll
        for (int i = 0; i < 2; i++) {
          int row = wr * 32 + i * 16 + r16;
          int S = row * 4 + ((k8g + (row >> 1)) & 3);
          ax_[i] = *(const bf16x8*)(ldsT(buf, 0) + S * 16);
          ah_[i] = *(const bf16x8*)(ldsT(buf, 1) + S * 16);
        }
#pragma unroll
        for (int s = 0; s < 6; s++) {
#pragma unroll
          for (int j = 0; j < 2; j++) {
            int row = wc * 32 + j * 16 + r16;
            int S = row * 4 + ((k8g + (row >> 1)) & 3);
            bf16x8 b = *(const bf16x8*)(ldsT(buf, 2 + s) + S * 16);
#pragma unroll
            for (int i = 0; i < 2; i++)
              acc[s][i][j] = __builtin_amdgcn_mfma_f32_16x16x32_bf16(
                  (s < 3) ? ax_[i] : ah_[i], b, acc[s][i][j], 0, 0, 0);
          }
        }
      };
      stage(0, 0);
      __syncthreads();
      for (int it = 0; it < 19; ++it) {
        if (it + 1 < 19) stage((it + 1) & 1, (it + 1) * 32);
        compute(it & 1);
        __syncthreads();
      }
      const float* dprev = t ? (out_t - (size_t)NB * OUTW) : p.init_deter;
      const int dstr = t ? OUTW : DET;
#pragma unroll
      for (int j = 0; j < 2; j++) {
        int n = An0 + wc * 32 + j * 16 + r16;
        bool nok = (n < DET);   // pads never written: they only multiply zero W-cols
        float bihr = nok ? p.b_ih[n] : 0.f, bhhr = nok ? p.b_hh[n] : 0.f;
        float bihz = nok ? p.b_ih[600 + n] : 0.f, bhhz = nok ? p.b_hh[600 + n] : 0.f;
        float bihn = nok ? p.b_ih[1200 + n] : 0.f, bhhn = nok ? p.b_hh[1200 + n] : 0.f;
#pragma unroll
        for (int i = 0; i < 2; i++) {
          int mb = Am0 + wr * 32 + i * 16 + k8g * 4;
#pragma unroll
          for (int r = 0; r < 4; r++) {
            int m = mb + r;
            float dp = nok ? dprev[(size_t)m * dstr + n] : 0.f;  // unique addr -> plain load
            float rg = sigm(acc[0][i][j][r] + bihr + acc[3][i][j][r] + bhhr);
            float zg = sigm(acc[1][i][j][r] + bihz + acc[4][i][j][r] + bhhz);
            float ng = tanhf(acc[2][i][j][r] + bihn + rg * (acc[5][i][j][r] + bhhn));
            float h = (1.f - zg) * ng + zg * dp;
            u32 hb16 = f2bf(h);
            u32 other = (u32)__shfl_xor((int)hb16, 1, 64);  // partner has n^1
            if (nok) {
              st32sc((u32*)&out_t[(size_t)m * OUTW + n], __float_as_uint(h));
              if (!(lane & 1))   // n even; pair (n,n+1) both < 600
                st32sc((u32*)&hnow[(size_t)m * DP + n], hb16 | (other << 16));
            }
          }
        }
      }
    }
    gridbar(p.bar, 2 * t + 1);

    // =================== phase B: heads + sampling + xnext ===================
    if (doB) {
      const bool donext = (t + 1 < NT);
      const float* noise = (head ? p.noise_q : p.noise_p) + (size_t)t * NB * 32;

      // stage h slice [16][608] -> hsl [16][616] (plain cached; lines fresh)
      {
        const u16* hrow = hnow + (size_t)Bm0 * DP;
#pragma unroll
        for (int c = 0; c < 5; ++c) {
          int chunk = c * 256 + tid;
          char* ldst = (char*)hsl + (c * 256 + w * 64) * 16;  // wave-uniform base
          if (chunk < 1232) {
            int row = chunk / 77, cc = chunk - row * 77;
            int scc = cc < 76 ? cc : 75;
            gll16(hrow + (size_t)row * DP + scc * 8, ldst);
          }
        }
      }
      // zero ph pad cols 608..647 and xin
      for (int i = tid; i < 320; i += 256) {
        int r = i / 20, c = i - r * 20;
        *(u32*)&ph[r * 648 + 608 + 2 * c] = 0;
      }
      if (donext)
        for (int i = tid; i < 576; i += 256) ((u32*)xin)[i] = 0;
      __syncthreads();

      // ---- heads1: [16 rows] x [608 cols], K=608; A from LDS, W1 from L2
      f32x4 a1[10] = {};
      for (int kc = 0; kc < DP; kc += 32) {
        bf16x8 fa = *(const bf16x8*)&hsl[r16 * 616 + kc + k8g * 8];
#pragma unroll
        for (int i = 0; i < 10; i++) {
          int j = w + i * 4;
          if (j < 38) {
            bf16x8 fb = *(const bf16x8*)&W1[(size_t)(j * 16 + r16) * DP + kc + k8g * 8];
            a1[i] = __builtin_amdgcn_mfma_f32_16x16x32_bf16(fa, fb, a1[i], 0, 0, 0);
          }
        }
      }
      // ph epilogue: elu(+bias +QE) -> LDS bf16
#pragma unroll
      for (int i = 0; i < 10; i++) {
        int j = w + i * 4;
        if (j >= 38) break;
        int n = j * 16 + r16;
#pragma unroll
        for (int r = 0; r < 4; r++) {
          int mrow = k8g * 4 + r, m = Bm0 + mrow;
          float v = a1[i][r];
          if (n < DET) {
            v += b1[n];
            if (head) v += bf2f(p.QE[((size_t)t * NB + m) * NP + n]);
            ph[mrow * 648 + n] = f2bf(eluf(v));
          } else {
            ph[mrow * 648 + n] = 0;
          }
        }
      }
      __syncthreads();
      // ---- heads2: K=640 split over 4 waves (160 each), LDS reduce
      f32x4 a2[4] = {};
      {
        int kc0 = w * 160;
#pragma unroll
        for (int ks = 0; ks < 5; ks++) {
          int kc = kc0 + ks * 32;
          bf16x8 fa = *(const bf16x8*)&ph[r16 * 648 + kc + k8g * 8];
#pragma unroll
          for (int j = 0; j < 4; j++) {
            bf16x8 fb = *(const bf16x8*)&W2[(size_t)(j * 16 + r16) * NP + kc + k8g * 8];
            a2[j] = __builtin_amdgcn_mfma_f32_16x16x32_bf16(fa, fb, a2[j], 0, 0, 0);
          }
        }
      }
      if (w) {
#pragma unroll
        for (int j = 0; j < 4; j++)
#pragma unroll
          for (int r = 0; r < 4; r++)
            red[(w - 1) * 1024 + (j * 16 + r16) * 16 + k8g * 4 + r] = a2[j][r];
      }
      __syncthreads();
      if (w == 0) {
#pragma unroll
        for (int j = 0; j < 4; j++)
#pragma unroll
          for (int r = 0; r < 4; r++) {
            int c = j * 16 + r16, mr = k8g * 4 + r;
            a2[j][r] += red[c * 16 + mr] + red[1024 + c * 16 + mr] + red[2048 + c * 16 + mr];
          }
        const int ob = head ? 696 : 600;
        const float* ntn = donext ? p.nonterm + (size_t)(t + 1) * NB : nullptr;
#pragma unroll
        for (int j = 0; j < 2; j++) {
          int c = j * 16 + r16;
          float bmu = b2[c], bsd = b2[32 + c];
#pragma unroll
          for (int r = 0; r < 4; r++) {
            int mr = k8g * 4 + r, m = Bm0 + mr;
            float mu = a2[j][r] + bmu;
            float sd = softplusf(a2[j + 2][r] + bsd) + 0.1f;
            float st = mu + sd * noise[(size_t)m * 32 + c];
            float* op = out_t + (size_t)m * OUTW + ob;
            op[c] = mu; op[32 + c] = sd; op[64 + c] = st;   // host-only: plain
            if (head && donext) xin[mr * 72 + c] = f2bf(st * ntn[m]);
          }
        }
      } else if (w == 1 && head && donext) {
        const float* an = p.actions + (size_t)(t + 1) * NB * 6;
#pragma unroll
        for (int rep = 0; rep < 2; rep++) {
          int idx = lane + rep * 64;
          if (idx < 96) {
            int rr = idx / 6, c = idx - rr * 6;
            xin[rr * 72 + 32 + c] = f2bf(an[(size_t)(Bm0 + rr) * 6 + c]);
          }
        }
      }
      if (head && donext) {
        __syncthreads();
        // xnext: [16][600] = elu(xin[16][64] @ Winp^T + b_in) -> xbuf[t+1]
        f32x4 xc[10] = {};
        const int nb = w * 160;
#pragma unroll
        for (int kc = 0; kc < 64; kc += 32) {
          bf16x8 fa = *(const bf16x8*)&xin[r16 * 72 + kc + k8g * 8];
#pragma unroll
          for (int j = 0; j < 10; j++) {
            bf16x8 fb = *(const bf16x8*)&p.Winp[(size_t)(nb + j * 16 + r16) * 64 + kc + k8g * 8];
            xc[j] = __builtin_amdgcn_mfma_f32_16x16x32_bf16(fa, fb, xc[j], 0, 0, 0);
          }
        }
#pragma unroll
        for (int j = 0; j < 10; j++) {
          int n = nb + j * 16 + r16;
          bool nok = (n < DET);
          float bi = nok ? p.b_in[n] : 0.f;
#pragma unroll
          for (int r = 0; r < 4; r++) {
            int m = Bm0 + k8g * 4 + r;
            float v = eluf(xc[j][r] + bi);
            u32 xb16 = f2bf(v);
            u32 other = (u32)__shfl_xor((int)xb16, 1, 64);
            if (nok && !(lane & 1))
              st32sc((u32*)&xnxt[(size_t)m * DP + n], xb16 | (other << 16));
          }
        }
      }
    }
    if (t + 1 < NT) gridbar(p.bar, 2 * t + 2);
  }
}

// ---------------- prolog GEMM (QE, x0) ---------------------------------------
struct GemmZ {
  const u16* A; int lda;
  const u16* B; int ldb;
  int K;
  const float* bias;
  u16* C; int ldc;
  int mode;   // 1: elu(x+bias[n<DET]) -> bf16, store n<DP ; 2: raw bf16, store n<ldc
};

__global__ __launch_bounds__(256, 2) void gemmP(GemmZ g)
{
  __shared__ u16 lA[2][128 * 32];
  __shared__ u16 lB[2][128 * 32];
  const int tid = threadIdx.x, lane = tid & 63, w = tid >> 6;
  const int wr = w >> 1, wc = w & 1;
  const size_t m0 = (size_t)blockIdx.y * 128;
  const int n0 = blockIdx.x * 128;
  const int r16 = lane & 15, k8g = lane >> 4;
  f32x4 acc[4][4] = {};

  const int S0 = tid, S1 = tid + 256;
  const int ar0 = S0 >> 2, ak0 = (((S0 & 3) - ((S0 >> 3) & 3)) & 3) * 8;
  const int ar1 = S1 >> 2, ak1 = (((S1 & 3) - ((S1 >> 3) & 3)) & 3) * 8;
  const int lo = w * 1024;
  const int niter = g.K / 32;

  auto stage = [&](int buf, int kc) {
    gll16(g.A + (m0 + ar0) * (size_t)g.lda + kc + ak0, (char*)lA[buf] + lo);
    gll16(g.A + (m0 + ar1) * (size_t)g.lda + kc + ak1, (char*)lA[buf] + 4096 + lo);
    gll16(g.B + (size_t)(n0 + ar0) * g.ldb + kc + ak0, (char*)lB[buf] + lo);
    gll16(g.B + (size_t)(n0 + ar1) * g.ldb + kc + ak1, (char*)lB[buf] + 4096 + lo);
  };
  auto compute = [&](int buf) {
    bf16x8 fa[4], fb[4];
#pragma unroll
    for (int i = 0; i < 4; i++) {
      int row = wr * 64 + i * 16 + r16;
      int S = row * 4 + ((k8g + (row >> 1)) & 3);
      fa[i] = *(const bf16x8*)((const char*)lA[buf] + S * 16);
    }
#pragma unroll
    for (int j = 0; j < 4; j++) {
      int row = wc * 64 + j * 16 + r16;
      int S = row * 4 + ((k8g + (row >> 1)) & 3);
      fb[j] = *(const bf16x8*)((const char*)lB[buf] + S * 16);
    }
#pragma unroll
    for (int i = 0; i < 4; i++)
#pragma unroll
      for (int j = 0; j < 4; j++)
        acc[i][j] = __builtin_amdgcn_mfma_f32_16x16x32_bf16(fa[i], fb[j], acc[i][j], 0, 0, 0);
  };

  stage(0, 0);
  __syncthreads();
  for (int it = 0; it < niter; ++it) {
    if (it + 1 < niter) stage((it + 1) & 1, (it + 1) * 32);
    compute(it & 1);
    __syncthreads();
  }

#pragma unroll
  for (int i = 0; i < 4; i++) {
    size_t mb = m0 + wr * 64 + i * 16 + k8g * 4;
#pragma unroll
    for (int j = 0; j < 4; j++) {
      int n = n0 + wc * 64 + j * 16 + r16;
      if (g.mode == 1) {
        if (n >= DP) continue;
        float b = (n < DET) ? g.bias[n] : 0.f;
#pragma unroll
        for (int r = 0; r < 4; r++)
          g.C[(mb + r) * (size_t)g.ldc + n] = f2bf(eluf(acc[i][j][r] + b));
      } else {
        if (n >= g.ldc) continue;
#pragma unroll
        for (int r = 0; r < 4; r++)
          g.C[(mb + r) * (size_t)g.ldc + n] = f2bf(acc[i][j][r]);
      }
    }
  }
}

// ---------------- small prolog kernels ---------------------------------------
__global__ void wconv_k(const float* src, int srows, int scols, int sstride,
                        u16* dst, int drows, int dstride, int c0, int cw)
{
  int idx = blockIdx.x * 256 + threadIdx.x;
  if (idx >= drows * cw) return;
  int r = idx / cw, c = idx - r * cw;
  float v = (r < srows && c < scols) ? src[(size_t)r * sstride + c] : 0.f;
  dst[(size_t)r * dstride + c0 + c] = f2bf(v);
}

__global__ void conv8_k(const float* src, u16* dst, int n8)
{
  int i = blockIdx.x * 256 + threadIdx.x;
  if (i >= n8) return;
  const float4* s = (const float4*)(src + (size_t)i * 8);
  float4 f0 = s[0], f1 = s[1];
  union { u16 h[8]; int4 v; } cv;
  cv.h[0] = f2bf(f0.x); cv.h[1] = f2bf(f0.y); cv.h[2] = f2bf(f0.z); cv.h[3] = f2bf(f0.w);
  cv.h[4] = f2bf(f1.x); cv.h[5] = f2bf(f1.y); cv.h[6] = f2bf(f1.z); cv.h[7] = f2bf(f1.w);
  *(int4*)(dst + (size_t)i * 8) = cv.v;
}

__global__ void xin0_k(const float* stoc0, const float* nt0, const float* act0, u16* xing)
{
  int i = blockIdx.x * 256 + threadIdx.x;
  if (i >= NB * 64) return;
  int m = i >> 6, c = i & 63;
  float v = 0.f;
  if (c < 32) v = stoc0[m * 32 + c] * nt0[m];
  else if (c < 38) v = act0[m * 6 + (c - 32)];
  xing[i] = f2bf(v);
}

// ---------------- host --------------------------------------------------------
extern "C" void kernel_launch(void* const* d_in, const int* in_sizes, int n_in,
                              void* d_out, int out_size, void* d_ws, size_t ws_size,
                              hipStream_t stream)
{
  const float* actions    = (const float*)d_in[0];
  const float* nonterm    = (const float*)d_in[1];
  const float* emb        = (const float*)d_in[2];
  const float* noise_p    = (const float*)d_in[3];
  const float* noise_q    = (const float*)d_in[4];
  const float* init_deter = (const float*)d_in[5];
  const float* init_stoc  = (const float*)d_in[6];
  const float* W_in = (const float*)d_in[7];
  const float* b_in = (const float*)d_in[8];
  const float* W_ih = (const float*)d_in[9];
  const float* b_ih = (const float*)d_in[10];
  const float* W_hh = (const float*)d_in[11];
  const float* b_hh = (const float*)d_in[12];
  const float* Wp1 = (const float*)d_in[13];
  const float* bp1 = (const float*)d_in[14];
  const float* Wp2 = (const float*)d_in[15];
  const float* bp2 = (const float*)d_in[16];
  const float* Wq1 = (const float*)d_in[17];
  const float* bq1 = (const float*)d_in[18];
  const float* Wq2 = (const float*)d_in[19];
  const float* bq2 = (const float*)d_in[20];
  float* out = (float*)d_out;

  char* wsp = (char*)d_ws;
  size_t o = 0;
  auto alloc = [&](size_t b) { char* pp = wsp + o; o = (o + b + 255) & ~(size_t)255; return pp; };
  u16* W6   = (u16*)alloc(6ull * NP * DP * 2);
  u16* Wp1p = (u16*)alloc((size_t)NP * DP * 2);
  u16* Wq1h = (u16*)alloc((size_t)NP * DP * 2);
  u16* Wq1e = (u16*)alloc((size_t)NP * EMB * 2);
  u16* Wp2p = (u16*)alloc(64ull * NP * 2);
  u16* Wq2p = (u16*)alloc(64ull * NP * 2);
  u16* Winp = (u16*)alloc((size_t)NP * 64 * 2);
  u16* xing = (u16*)alloc((size_t)NB * 64 * 2);
  u32* barp = (u32*)alloc(4096);
  u16* xbuf = (u16*)alloc(HXS * 2 * (NT + 1));   // x_t, t=0..49 (+1 slack)
  u16* hbuf = (u16*)alloc(HXS * 2 * (NT + 1));   // h_{t-1}, t=0..50
  u16* embb = (u16*)alloc((size_t)NT * NB * EMB * 2);
  u16* QE   = (u16*)alloc((size_t)NT * NB * NP * 2);
  if (o > ws_size) return;  // need ~310MB; ws observed ~800MB

  hipMemsetAsync(barp, 0, 4096, stream);  // barrier counters re-init each call

  auto wcl = [&](const float* src, int sr, int sc, int ss, u16* dst, int dr, int ds, int c0, int cw) {
    int n = dr * cw;
    wconv_k<<<(n + 255) / 256, 256, 0, stream>>>(src, sr, sc, ss, dst, dr, ds, c0, cw);
  };
  for (int s = 0; s < 3; s++) {
    wcl(W_ih + (size_t)s * 600 * 600, 600, 600, 600, W6 + (size_t)s * NP * DP, NP, DP, 0, DP);
    wcl(W_hh + (size_t)s * 600 * 600, 600, 600, 600, W6 + (size_t)(3 + s) * NP * DP, NP, DP, 0, DP);
  }
  wcl(Wp1, 600, 600, 600, Wp1p, NP, DP, 0, DP);
  wcl(Wq1, 600, 600, 1624, Wq1h, NP, DP, 0, DP);
  wcl(Wq1 + 600, 600, 1024, 1624, Wq1e, NP, EMB, 0, EMB);
  wcl(Wp2, 64, 600, 600, Wp2p, 64, NP, 0, NP);
  wcl(Wq2, 64, 600, 600, Wq2p, 64, NP, 0, NP);
  wcl(W_in, 600, 38, 38, Winp, NP, 64, 0, 64);
  wcl(init_deter, 1024, 600, 600, hbuf, 1024, DP, 0, DP);   // hbuf[0]

  // QE = emb @ Wq1e^T for all T (h-independent, off critical path)
  {
    int n8 = NT * NB * EMB / 8;
    conv8_k<<<(n8 + 255) / 256, 256, 0, stream>>>(emb, embb, n8);
    GemmZ gq = { embb, EMB, Wq1e, EMB, EMB, nullptr, QE, NP, 2 };
    gemmP<<<dim3(5, 400, 1), 256, 0, stream>>>(gq);
  }
  // x_0 -> xbuf[0]
  xin0_k<<<NB * 64 / 256, 256, 0, stream>>>(init_stoc, nonterm, actions, xing);
  {
    GemmZ gx = { xing, 64, Winp, 64, 64, b_in, xbuf, DP, 1 };
    gemmP<<<dim3(5, 8, 1), 256, 0, stream>>>(gx);
  }

  // persistent rollout: 160 blocks x 64KB LDS -> co-resident by capacity.
  PK pk = { W6, Wp1p, Wq1h, Wp2p, Wq2p, Winp, QE,
            b_ih, b_hh, bp1, bq1, bp2, bq2, b_in,
            init_deter, actions, nonterm, noise_p, noise_q,
            xbuf, hbuf, out, barp };
  rssm_persist<<<GBLK, 256, 0, stream>>>(pk);
}

// Round 8
// 5796.004 us; speedup vs baseline: 1.3888x; 1.0729x over previous
//
#include <hip/hip_runtime.h>

typedef __bf16 bf16x8 __attribute__((ext_vector_type(8)));
typedef float f32x4 __attribute__((ext_vector_type(4)));
typedef unsigned short u16;
typedef unsigned int u32;
typedef unsigned long long u64;

#define NT 50
#define NB 1024
#define DET 600
#define DP 608        // padded K dim 600 -> 19*32
#define NP 640        // padded N dim 600 -> 5*128
#define HLD 640       // h/x row stride: 640*2B = 1280B = 10 cache lines (line-aligned)
#define EMB 1024
#define OUTW 792
#define GBLK 160      // persistent grid: phase A=160 tiles, phase B=128 slices
#define SUBN 8
#define BPS (GBLK / SUBN)
#define HXS2 ((size_t)NB * HLD)

__device__ __forceinline__ u16 f2bf(float f) {
  unsigned u = __float_as_uint(f);
  u += 0x7FFFu + ((u >> 16) & 1u);
  return (u16)(u >> 16);
}
__device__ __forceinline__ float bf2f(u16 h) { return __uint_as_float(((unsigned)h) << 16); }
__device__ __forceinline__ float eluf(float x) { return x > 0.f ? x : expm1f(x); }
__device__ __forceinline__ float sigm(float x) { return 1.f / (1.f + expf(-x)); }
__device__ __forceinline__ float softplusf(float x) {
  return fmaxf(x, 0.f) + log1pf(expf(-fabsf(x)));
}

// async global->LDS, 16B/lane, cached path.
__device__ __forceinline__ void gll16(const void* g, void* l) {
  __builtin_amdgcn_global_load_lds(
      (const __attribute__((address_space(1))) u32*)g,
      (__attribute__((address_space(3))) u32*)l, 16, 0, 0);
}

// Grid barrier with L2 writeback: plain cached stores -> __syncthreads drains
// them into L2 -> buffer_wbl2 sc1 flushes dirty L2 lines to L3 (no invalidate,
// L2 stays warm) -> relaxed system atomics order the release. Readers use plain
// loads: their L2 copies are either self-written (current) or virgin (fetch L3).
__device__ __forceinline__ void gridbar(u32* bar, u32 target) {
  __syncthreads();   // per-wave s_waitcnt vmcnt(0): all stores in L2
  if (threadIdx.x == 0) {
    asm volatile("buffer_wbl2 sc1\n\ts_waitcnt vmcnt(0)" ::: "memory");
    const int sub = blockIdx.x & 7;
    u32 a = __hip_atomic_fetch_add(&bar[sub * 32], 1u, __ATOMIC_RELAXED,
                                   __HIP_MEMORY_SCOPE_SYSTEM);
    bool done = false;
    if (a == target * BPS - 1) {
      u32 r = __hip_atomic_fetch_add(&bar[8 * 32], 1u, __ATOMIC_RELAXED,
                                     __HIP_MEMORY_SCOPE_SYSTEM);
      if (r == target * SUBN - 1) {
        __hip_atomic_store(&bar[9 * 32], target, __ATOMIC_RELAXED,
                           __HIP_MEMORY_SCOPE_SYSTEM);
        done = true;
      }
    }
    if (!done) {
      while (__hip_atomic_load(&bar[9 * 32], __ATOMIC_RELAXED,
                               __HIP_MEMORY_SCOPE_SYSTEM) < target)
        __builtin_amdgcn_s_sleep(2);
    }
    __builtin_amdgcn_sched_barrier(0);
  }
  __syncthreads();
}

// Swizzled chunk layout for [rows][32] bf16 tiles staged as 16B chunks:
// chunk S holds (row = S>>2, k8 = ((S&3) - ((S>>3)&3)) & 3).
// reader for (row,k8): S = row*4 + ((k8 + (row>>1)) & 3)  -> 2-way banks (free).

struct PK {
  const u16 *W6, *Wp1, *Wq1h, *Wp2, *Wq2, *Winp, *QE;
  const float *b_ih, *b_hh, *bp1, *bq1, *bp2, *bq2, *b_in;
  const float *init_deter, *actions, *nonterm, *noise_p, *noise_q;
  u16 *xbuf, *hbuf;    // per-step unique buffers, row stride HLD
  float *out;
  u32 *bar;
};

__global__ __launch_bounds__(256, 1) void rssm_persist(PK p)
{
  __shared__ char smem[65536] __attribute__((aligned(16)));

  const int bid = blockIdx.x, tid = threadIdx.x;
  const int lane = tid & 63, w = tid >> 6;
  const int r16 = lane & 15, k8g = lane >> 4;

  // ----- phase A: 2-D XCD-affine mapping. XCD = bid%8 = (my%4)*2 + (nx%2):
  // per-XCD weight cols = 5 n-tiles (2.3MB, L2-fits); x/h rows read by 2 XCDs.
  const int xg = bid & 7, gg = bid >> 3;          // gg in 0..19
  const int my = (gg & 3) * 4 + (xg >> 1);        // 0..15
  const int nx = (gg >> 2) * 2 + (xg & 1);        // 0..9
  const int Am0 = my * 64, An0 = nx * 64;
  const int wr = w >> 1, wc = w & 1;
  const int srow = tid >> 2;
  const int sk8 = ((tid & 3) - ((tid >> 3) & 3)) & 3;
  const int lo = w * 1024;
  const u16* bw[6];
#pragma unroll
  for (int s = 0; s < 6; s++)
    bw[s] = p.W6 + (size_t)s * NP * DP + (size_t)(An0 + srow) * DP + sk8 * 8;
  const size_t aoff = (size_t)(Am0 + srow) * HLD + sk8 * 8;

  // ----- phase B config (heads for 16-row slice x head), bid 0..127
  const bool doB = bid < 128;
  const int slice = bid >> 1, head = bid & 1;
  const int Bm0 = slice * 16;
  const u16* W1 = head ? p.Wq1h : p.Wp1;
  const float* b1 = head ? p.bq1 : p.bp1;
  const u16* W2 = head ? p.Wq2 : p.Wp2;
  const float* b2 = head ? p.bq2 : p.bp2;

  u16* hsl = (u16*)smem;                     // [16][616] bf16
  u16* ph  = (u16*)(smem + 19712);           // [16][648] bf16
  float* red = (float*)(smem + 40448);       // [3][64][16] f32
  u16* xin = (u16*)(smem + 52736);           // [16][72] bf16

  for (int t = 0; t < NT; ++t) {
    const u16* hprev = p.hbuf + (size_t)t * HXS2;
    u16* hnow = p.hbuf + (size_t)(t + 1) * HXS2;
    const u16* xcur = p.xbuf + (size_t)t * HXS2;
    u16* xnxt = p.xbuf + (size_t)(t + 1) * HXS2;
    float* out_t = p.out + (size_t)t * NB * OUTW;

    // =================== phase A: GRU ===================
    {
      const u16* axp = xcur + aoff;
      const u16* ahp = hprev + aoff;
      auto ldsT = [&](int buf, int tile) -> char* { return smem + buf * 32768 + tile * 4096; };
      f32x4 acc[6][2][2] = {};
      auto stage = [&](int buf, int kc) {
        gll16(axp + kc, ldsT(buf, 0) + lo);
        gll16(ahp + kc, ldsT(buf, 1) + lo);
#pragma unroll
        for (int s = 0; s < 6; s++) gll16(bw[s] + kc, ldsT(buf, 2 + s) + lo);
      };
      auto compute = [&](int buf) {
        bf16x8 ax_[2], ah_[2];
#pragma unroll
        for (int i = 0; i < 2; i++) {
          int row = wr * 32 + i * 16 + r16;
          int S = row * 4 + ((k8g + (row >> 1)) & 3);
          ax_[i] = *(const bf16x8*)(ldsT(buf, 0) + S * 16);
          ah_[i] = *(const bf16x8*)(ldsT(buf, 1) + S * 16);
        }
#pragma unroll
        for (int s = 0; s < 6; s++) {
#pragma unroll
          for (int j = 0; j < 2; j++) {
            int row = wc * 32 + j * 16 + r16;
            int S = row * 4 + ((k8g + (row >> 1)) & 3);
            bf16x8 b = *(const bf16x8*)(ldsT(buf, 2 + s) + S * 16);
#pragma unroll
            for (int i = 0; i < 2; i++)
              acc[s][i][j] = __builtin_amdgcn_mfma_f32_16x16x32_bf16(
                  (s < 3) ? ax_[i] : ah_[i], b, acc[s][i][j], 0, 0, 0);
          }
        }
      };
      // software-pipelined K loop: counted vmcnt keeps prev-buffer wait only;
      // next-tile loads stay in flight across the barrier (guide T4).
      stage(0, 0);
      for (int it = 0; it < 19; ++it) {
        if (it + 1 < 19) {
          stage((it + 1) & 1, (it + 1) * 32);
          asm volatile("s_waitcnt vmcnt(8)" ::: "memory");
        } else {
          asm volatile("s_waitcnt vmcnt(0)" ::: "memory");
        }
        __builtin_amdgcn_s_barrier();
        __builtin_amdgcn_sched_barrier(0);
        compute(it & 1);
        __builtin_amdgcn_s_barrier();
      }
      const float* dprev = t ? (out_t - (size_t)NB * OUTW) : p.init_deter;
      const int dstr = t ? OUTW : DET;
#pragma unroll
      for (int j = 0; j < 2; j++) {
        int n = An0 + wc * 32 + j * 16 + r16;
        bool nok = (n < DET);
        float bihr = nok ? p.b_ih[n] : 0.f, bhhr = nok ? p.b_hh[n] : 0.f;
        float bihz = nok ? p.b_ih[600 + n] : 0.f, bhhz = nok ? p.b_hh[600 + n] : 0.f;
        float bihn = nok ? p.b_ih[1200 + n] : 0.f, bhhn = nok ? p.b_hh[1200 + n] : 0.f;
#pragma unroll
        for (int i = 0; i < 2; i++) {
          int mb = Am0 + wr * 32 + i * 16 + k8g * 4;
#pragma unroll
          for (int r = 0; r < 4; r++) {
            int m = mb + r;
            float dp = nok ? dprev[(size_t)m * dstr + n] : 0.f;
            float rg = sigm(acc[0][i][j][r] + bihr + acc[3][i][j][r] + bhhr);
            float zg = sigm(acc[1][i][j][r] + bihz + acc[4][i][j][r] + bhhz);
            float ng = tanhf(acc[2][i][j][r] + bihn + rg * (acc[5][i][j][r] + bhhn));
            float h = (1.f - zg) * ng + zg * dp;
            u32 hb16 = f2bf(h);
            u32 other = (u32)__shfl_xor((int)hb16, 1, 64);
            if (nok) {
              out_t[(size_t)m * OUTW + n] = h;                       // plain store
              if (!(lane & 1))
                *(u32*)&hnow[(size_t)m * HLD + n] = hb16 | (other << 16);
            }
          }
        }
      }
    }
    gridbar(p.bar, 2 * t + 1);

    // =================== phase B: heads + sampling + xnext ===================
    if (doB) {
      const bool donext = (t + 1 < NT);
      const float* noise = (head ? p.noise_q : p.noise_p) + (size_t)t * NB * 32;

      // stage h slice [16][608] -> hsl [16][616] (plain cached)
      {
        const u16* hrow = hnow + (size_t)Bm0 * HLD;
#pragma unroll
        for (int c = 0; c < 5; ++c) {
          int chunk = c * 256 + tid;
          char* ldst = (char*)hsl + (c * 256 + w * 64) * 16;
          if (chunk < 1232) {
            int row = chunk / 77, cc = chunk - row * 77;
            int scc = cc < 76 ? cc : 75;
            gll16(hrow + (size_t)row * HLD + scc * 8, ldst);
          }
        }
      }
      // QE prefetch (overlaps hsl staging + heads1); QE cols 600-639 are zero.
      float qe[10][4] = {};
      if (head) {
        const u16* qbase = p.QE + ((size_t)t * NB + Bm0) * NP;
#pragma unroll
        for (int i = 0; i < 10; i++) {
          int j = w + i * 4;
          if (j < 38) {
            int n = j * 16 + r16;
#pragma unroll
            for (int r = 0; r < 4; r++)
              qe[i][r] = bf2f(qbase[(size_t)(k8g * 4 + r) * NP + n]);
          }
        }
      }
      // zero ph pad cols 608..647 and xin
      for (int i = tid; i < 320; i += 256) {
        int r = i / 20, c = i - r * 20;
        *(u32*)&ph[r * 648 + 608 + 2 * c] = 0;
      }
      if (donext)
        for (int i = tid; i < 576; i += 256) ((u32*)xin)[i] = 0;
      __syncthreads();

      // ---- heads1: [16 rows] x [608 cols], K=608; A from LDS, W1 from L2
      f32x4 a1[10] = {};
      for (int kc = 0; kc < DP; kc += 32) {
        bf16x8 fa = *(const bf16x8*)&hsl[r16 * 616 + kc + k8g * 8];
#pragma unroll
        for (int i = 0; i < 10; i++) {
          int j = w + i * 4;
          if (j < 38) {
            bf16x8 fb = *(const bf16x8*)&W1[(size_t)(j * 16 + r16) * DP + kc + k8g * 8];
            a1[i] = __builtin_amdgcn_mfma_f32_16x16x32_bf16(fa, fb, a1[i], 0, 0, 0);
          }
        }
      }
      // ph epilogue: elu(+bias +QE) -> LDS bf16
#pragma unroll
      for (int i = 0; i < 10; i++) {
        int j = w + i * 4;
        if (j >= 38) break;
        int n = j * 16 + r16;
#pragma unroll
        for (int r = 0; r < 4; r++) {
          int mrow = k8g * 4 + r;
          float v = a1[i][r];
          if (n < DET) {
            v += b1[n] + qe[i][r];
            ph[mrow * 648 + n] = f2bf(eluf(v));
          } else {
            ph[mrow * 648 + n] = 0;
          }
        }
      }
      __syncthreads();
      // ---- heads2: K=640 split over 4 waves, LDS reduce
      f32x4 a2[4] = {};
      {
        int kc0 = w * 160;
#pragma unroll
        for (int ks = 0; ks < 5; ks++) {
          int kc = kc0 + ks * 32;
          bf16x8 fa = *(const bf16x8*)&ph[r16 * 648 + kc + k8g * 8];
#pragma unroll
          for (int j = 0; j < 4; j++) {
            bf16x8 fb = *(const bf16x8*)&W2[(size_t)(j * 16 + r16) * NP + kc + k8g * 8];
            a2[j] = __builtin_amdgcn_mfma_f32_16x16x32_bf16(fa, fb, a2[j], 0, 0, 0);
          }
        }
      }
      if (w) {
#pragma unroll
        for (int j = 0; j < 4; j++)
#pragma unroll
          for (int r = 0; r < 4; r++)
            red[(w - 1) * 1024 + (j * 16 + r16) * 16 + k8g * 4 + r] = a2[j][r];
      }
      __syncthreads();
      if (w == 0) {
#pragma unroll
        for (int j = 0; j < 4; j++)
#pragma unroll
          for (int r = 0; r < 4; r++) {
            int c = j * 16 + r16, mr = k8g * 4 + r;
            a2[j][r] += red[c * 16 + mr] + red[1024 + c * 16 + mr] + red[2048 + c * 16 + mr];
          }
        const int ob = head ? 696 : 600;
        const float* ntn = donext ? p.nonterm + (size_t)(t + 1) * NB : nullptr;
#pragma unroll
        for (int j = 0; j < 2; j++) {
          int c = j * 16 + r16;
          float bmu = b2[c], bsd = b2[32 + c];
#pragma unroll
          for (int r = 0; r < 4; r++) {
            int mr = k8g * 4 + r, m = Bm0 + mr;
            float mu = a2[j][r] + bmu;
            float sd = softplusf(a2[j + 2][r] + bsd) + 0.1f;
            float st = mu + sd * noise[(size_t)m * 32 + c];
            float* op = out_t + (size_t)m * OUTW + ob;
            op[c] = mu; op[32 + c] = sd; op[64 + c] = st;
            if (head && donext) xin[mr * 72 + c] = f2bf(st * ntn[m]);
          }
        }
      } else if (w == 1 && head && donext) {
        const float* an = p.actions + (size_t)(t + 1) * NB * 6;
#pragma unroll
        for (int rep = 0; rep < 2; rep++) {
          int idx = lane + rep * 64;
          if (idx < 96) {
            int rr = idx / 6, c = idx - rr * 6;
            xin[rr * 72 + 32 + c] = f2bf(an[(size_t)(Bm0 + rr) * 6 + c]);
          }
        }
      }
      if (head && donext) {
        __syncthreads();
        // xnext: elu(xin[16][64] @ Winp^T + b_in) -> xbuf[t+1]
        f32x4 xc[10] = {};
        const int nb = w * 160;
#pragma unroll
        for (int kc = 0; kc < 64; kc += 32) {
          bf16x8 fa = *(const bf16x8*)&xin[r16 * 72 + kc + k8g * 8];
#pragma unroll
          for (int j = 0; j < 10; j++) {
            bf16x8 fb = *(const bf16x8*)&p.Winp[(size_t)(nb + j * 16 + r16) * 64 + kc + k8g * 8];
            xc[j] = __builtin_amdgcn_mfma_f32_16x16x32_bf16(fa, fb, xc[j], 0, 0, 0);
          }
        }
#pragma unroll
        for (int j = 0; j < 10; j++) {
          int n = nb + j * 16 + r16;
          bool nok = (n < DET);
          float bi = nok ? p.b_in[n] : 0.f;
#pragma unroll
          for (int r = 0; r < 4; r++) {
            int m = Bm0 + k8g * 4 + r;
            float v = eluf(xc[j][r] + bi);
            u32 xb16 = f2bf(v);
            u32 other = (u32)__shfl_xor((int)xb16, 1, 64);
            if (nok && !(lane & 1))
              *(u32*)&xnxt[(size_t)m * HLD + n] = xb16 | (other << 16);
          }
        }
      }
    }
    if (t + 1 < NT) gridbar(p.bar, 2 * t + 2);
  }
}

// ---------------- prolog GEMM (QE, x0) ---------------------------------------
struct GemmZ {
  const u16* A; int lda;
  const u16* B; int ldb;
  int K;
  const float* bias;
  u16* C; int ldc;
  int mode;   // 1: elu(x+bias[n<DET]) -> bf16, store n<DP ; 2: raw bf16, store n<ldc
};

__global__ __launch_bounds__(256, 2) void gemmP(GemmZ g)
{
  __shared__ u16 lA[2][128 * 32];
  __shared__ u16 lB[2][128 * 32];
  const int tid = threadIdx.x, lane = tid & 63, w = tid >> 6;
  const int wr = w >> 1, wc = w & 1;
  const size_t m0 = (size_t)blockIdx.y * 128;
  const int n0 = blockIdx.x * 128;
  const int r16 = lane & 15, k8g = lane >> 4;
  f32x4 acc[4][4] = {};

  const int S0 = tid, S1 = tid + 256;
  const int ar0 = S0 >> 2, ak0 = (((S0 & 3) - ((S0 >> 3) & 3)) & 3) * 8;
  const int ar1 = S1 >> 2, ak1 = (((S1 & 3) - ((S1 >> 3) & 3)) & 3) * 8;
  const int lo = w * 1024;
  const int niter = g.K / 32;

  auto stage = [&](int buf, int kc) {
    gll16(g.A + (m0 + ar0) * (size_t)g.lda + kc + ak0, (char*)lA[buf] + lo);
    gll16(g.A + (m0 + ar1) * (size_t)g.lda + kc + ak1, (char*)lA[buf] + 4096 + lo);
    gll16(g.B + (size_t)(n0 + ar0) * g.ldb + kc + ak0, (char*)lB[buf] + lo);
    gll16(g.B + (size_t)(n0 + ar1) * g.ldb + kc + ak1, (char*)lB[buf] + 4096 + lo);
  };
  auto compute = [&](int buf) {
    bf16x8 fa[4], fb[4];
#pragma unroll
    for (int i = 0; i < 4; i++) {
      int row = wr * 64 + i * 16 + r16;
      int S = row * 4 + ((k8g + (row >> 1)) & 3);
      fa[i] = *(const bf16x8*)((const char*)lA[buf] + S * 16);
    }
#pragma unroll
    for (int j = 0; j < 4; j++) {
      int row = wc * 64 + j * 16 + r16;
      int S = row * 4 + ((k8g + (row >> 1)) & 3);
      fb[j] = *(const bf16x8*)((const char*)lB[buf] + S * 16);
    }
#pragma unroll
    for (int i = 0; i < 4; i++)
#pragma unroll
      for (int j = 0; j < 4; j++)
        acc[i][j] = __builtin_amdgcn_mfma_f32_16x16x32_bf16(fa[i], fb[j], acc[i][j], 0, 0, 0);
  };

  stage(0, 0);
  __syncthreads();
  for (int it = 0; it < niter; ++it) {
    if (it + 1 < niter) stage((it + 1) & 1, (it + 1) * 32);
    compute(it & 1);
    __syncthreads();
  }

#pragma unroll
  for (int i = 0; i < 4; i++) {
    size_t mb = m0 + wr * 64 + i * 16 + k8g * 4;
#pragma unroll
    for (int j = 0; j < 4; j++) {
      int n = n0 + wc * 64 + j * 16 + r16;
      if (g.mode == 1) {
        if (n >= DP) continue;
        float b = (n < DET) ? g.bias[n] : 0.f;
#pragma unroll
        for (int r = 0; r < 4; r++)
          g.C[(mb + r) * (size_t)g.ldc + n] = f2bf(eluf(acc[i][j][r] + b));
      } else {
        if (n >= g.ldc) continue;
#pragma unroll
        for (int r = 0; r < 4; r++)
          g.C[(mb + r) * (size_t)g.ldc + n] = f2bf(acc[i][j][r]);
      }
    }
  }
}

// ---------------- small prolog kernels ---------------------------------------
__global__ void wconv_k(const float* src, int srows, int scols, int sstride,
                        u16* dst, int drows, int dstride, int c0, int cw)
{
  int idx = blockIdx.x * 256 + threadIdx.x;
  if (idx >= drows * cw) return;
  int r = idx / cw, c = idx - r * cw;
  float v = (r < srows && c < scols) ? src[(size_t)r * sstride + c] : 0.f;
  dst[(size_t)r * dstride + c0 + c] = f2bf(v);
}

__global__ void conv8_k(const float* src, u16* dst, int n8)
{
  int i = blockIdx.x * 256 + threadIdx.x;
  if (i >= n8) return;
  const float4* s = (const float4*)(src + (size_t)i * 8);
  float4 f0 = s[0], f1 = s[1];
  union { u16 h[8]; int4 v; } cv;
  cv.h[0] = f2bf(f0.x); cv.h[1] = f2bf(f0.y); cv.h[2] = f2bf(f0.z); cv.h[3] = f2bf(f0.w);
  cv.h[4] = f2bf(f1.x); cv.h[5] = f2bf(f1.y); cv.h[6] = f2bf(f1.z); cv.h[7] = f2bf(f1.w);
  *(int4*)(dst + (size_t)i * 8) = cv.v;
}

__global__ void xin0_k(const float* stoc0, const float* nt0, const float* act0, u16* xing)
{
  int i = blockIdx.x * 256 + threadIdx.x;
  if (i >= NB * 64) return;
  int m = i >> 6, c = i & 63;
  float v = 0.f;
  if (c < 32) v = stoc0[m * 32 + c] * nt0[m];
  else if (c < 38) v = act0[m * 6 + (c - 32)];
  xing[i] = f2bf(v);
}

// ---------------- host --------------------------------------------------------
extern "C" void kernel_launch(void* const* d_in, const int* in_sizes, int n_in,
                              void* d_out, int out_size, void* d_ws, size_t ws_size,
                              hipStream_t stream)
{
  const float* actions    = (const float*)d_in[0];
  const float* nonterm    = (const float*)d_in[1];
  const float* emb        = (const float*)d_in[2];
  const float* noise_p    = (const float*)d_in[3];
  const float* noise_q    = (const float*)d_in[4];
  const float* init_deter = (const float*)d_in[5];
  const float* init_stoc  = (const float*)d_in[6];
  const float* W_in = (const float*)d_in[7];
  const float* b_in = (const float*)d_in[8];
  const float* W_ih = (const float*)d_in[9];
  const float* b_ih = (const float*)d_in[10];
  const float* W_hh = (const float*)d_in[11];
  const float* b_hh = (const float*)d_in[12];
  const float* Wp1 = (const float*)d_in[13];
  const float* bp1 = (const float*)d_in[14];
  const float* Wp2 = (const float*)d_in[15];
  const float* bp2 = (const float*)d_in[16];
  const float* Wq1 = (const float*)d_in[17];
  const float* bq1 = (const float*)d_in[18];
  const float* Wq2 = (const float*)d_in[19];
  const float* bq2 = (const float*)d_in[20];
  float* out = (float*)d_out;

  char* wsp = (char*)d_ws;
  size_t o = 0;
  auto alloc = [&](size_t b) { char* pp = wsp + o; o = (o + b + 255) & ~(size_t)255; return pp; };
  u16* W6   = (u16*)alloc(6ull * NP * DP * 2);
  u16* Wp1p = (u16*)alloc((size_t)NP * DP * 2);
  u16* Wq1h = (u16*)alloc((size_t)NP * DP * 2);
  u16* Wq1e = (u16*)alloc((size_t)NP * EMB * 2);
  u16* Wp2p = (u16*)alloc(64ull * NP * 2);
  u16* Wq2p = (u16*)alloc(64ull * NP * 2);
  u16* Winp = (u16*)alloc((size_t)NP * 64 * 2);
  u16* xing = (u16*)alloc((size_t)NB * 64 * 2);
  u32* barp = (u32*)alloc(4096);
  u16* xbuf = (u16*)alloc(HXS2 * 2 * (NT + 1));
  u16* hbuf = (u16*)alloc(HXS2 * 2 * (NT + 1));
  u16* embb = (u16*)alloc((size_t)NT * NB * EMB * 2);
  u16* QE   = (u16*)alloc((size_t)NT * NB * NP * 2);
  if (o > ws_size) return;  // need ~320MB; ws observed ~800MB

  hipMemsetAsync(barp, 0, 4096, stream);

  auto wcl = [&](const float* src, int sr, int sc, int ss, u16* dst, int dr, int ds, int c0, int cw) {
    int n = dr * cw;
    wconv_k<<<(n + 255) / 256, 256, 0, stream>>>(src, sr, sc, ss, dst, dr, ds, c0, cw);
  };
  for (int s = 0; s < 3; s++) {
    wcl(W_ih + (size_t)s * 600 * 600, 600, 600, 600, W6 + (size_t)s * NP * DP, NP, DP, 0, DP);
    wcl(W_hh + (size_t)s * 600 * 600, 600, 600, 600, W6 + (size_t)(3 + s) * NP * DP, NP, DP, 0, DP);
  }
  wcl(Wp1, 600, 600, 600, Wp1p, NP, DP, 0, DP);
  wcl(Wq1, 600, 600, 1624, Wq1h, NP, DP, 0, DP);
  wcl(Wq1 + 600, 600, 1024, 1624, Wq1e, NP, EMB, 0, EMB);
  wcl(Wp2, 64, 600, 600, Wp2p, 64, NP, 0, NP);
  wcl(Wq2, 64, 600, 600, Wq2p, 64, NP, 0, NP);
  wcl(W_in, 600, 38, 38, Winp, NP, 64, 0, 64);
  wcl(init_deter, 1024, 600, 600, hbuf, 1024, HLD, 0, DP);   // hbuf[0], stride HLD

  // QE = emb @ Wq1e^T for all T
  {
    int n8 = NT * NB * EMB / 8;
    conv8_k<<<(n8 + 255) / 256, 256, 0, stream>>>(emb, embb, n8);
    GemmZ gq = { embb, EMB, Wq1e, EMB, EMB, nullptr, QE, NP, 2 };
    gemmP<<<dim3(5, 400, 1), 256, 0, stream>>>(gq);
  }
  // x_0 -> xbuf[0]
  xin0_k<<<NB * 64 / 256, 256, 0, stream>>>(init_stoc, nonterm, actions, xing);
  {
    GemmZ gx = { xing, 64, Winp, 64, 64, b_in, xbuf, HLD, 1 };
    gemmP<<<dim3(5, 8, 1), 256, 0, stream>>>(gx);
  }

  PK pk = { W6, Wp1p, Wq1h, Wp2p, Wq2p, Winp, QE,
            b_ih, b_hh, bp1, bq1, bp2, bq2, b_in,
            init_deter, actions, nonterm, noise_p, noise_q,
            xbuf, hbuf, out, barp };
  rssm_persist<<<GBLK, 256, 0, stream>>>(pk);
}

// Round 9
// 5582.895 us; speedup vs baseline: 1.4418x; 1.0382x over previous
//
#include <hip/hip_runtime.h>

typedef __bf16 bf16x8 __attribute__((ext_vector_type(8)));
typedef float f32x4 __attribute__((ext_vector_type(4)));
typedef unsigned short u16;
typedef unsigned int u32;
typedef unsigned long long u64;

#define NT 50
#define NB 1024
#define DET 600
#define DP 608        // padded K dim 600 -> 19*32
#define NP 640        // padded N dim 600 -> 5*128
#define HLD 640       // h/x row stride: 640*2B = 1280B line-aligned
#define EMB 1024
#define OUTW 792
#define GBLK 160      // persistent grid: phase A=160 tiles, phase B=128 slices
#define HXS2 ((size_t)NB * HLD)

__device__ __forceinline__ u16 f2bf(float f) {
  unsigned u = __float_as_uint(f);
  u += 0x7FFFu + ((u >> 16) & 1u);
  return (u16)(u >> 16);
}
__device__ __forceinline__ float bf2f(u16 h) { return __uint_as_float(((unsigned)h) << 16); }
__device__ __forceinline__ float eluf(float x) { return x > 0.f ? x : expm1f(x); }
__device__ __forceinline__ float sigm(float x) { return 1.f / (1.f + expf(-x)); }
__device__ __forceinline__ float softplusf(float x) {
  return fmaxf(x, 0.f) + log1pf(expf(-fabsf(x)));
}

__device__ __forceinline__ void gll16(const void* g, void* l) {
  __builtin_amdgcn_global_load_lds(
      (const __attribute__((address_space(1))) u32*)g,
      (__attribute__((address_space(3))) u32*)l, 16, 0, 0);
}

// relaxed system-scope (sc0sc1): write-through / coherence-point access, no inv.
__device__ __forceinline__ u32 ld32sc(const u32* p_) {
  return __hip_atomic_load(p_, __ATOMIC_RELAXED, __HIP_MEMORY_SCOPE_SYSTEM);
}
__device__ __forceinline__ void st32sc(u32* p_, u32 v) {
  __hip_atomic_store(p_, v, __ATOMIC_RELAXED, __HIP_MEMORY_SCOPE_SYSTEM);
}

// Flag-array grid barrier: ZERO atomic RMWs. Arrival = one relaxed-system
// store per block; block 0 wave 0 polls all flags (3 loads/lane + __all),
// then stores a release flag; others spin on release. Monotone targets.
__device__ __forceinline__ u32 ldflag(const u32* bar, int i, u32 target) {
  return (i >= 1 && i < GBLK) ? ld32sc(&bar[i]) : target;   // block 0 has no flag
}
__device__ __forceinline__ void gridbar(u32* bar, u32 target) {
  __syncthreads();   // per-wave vmcnt(0): all data stores complete (SC at L3)
  if (blockIdx.x == 0) {
    if (threadIdx.x < 64) {
      const int l = threadIdx.x;
      for (;;) {
        u32 a = ldflag(bar, l, target);
        u32 b = ldflag(bar, l + 64, target);
        u32 c = ldflag(bar, l + 128, target);
        u32 mn = min(min(a, b), c);
        if (__all(mn >= target)) break;
        __builtin_amdgcn_s_sleep(2);
      }
      if (l == 0) st32sc(&bar[GBLK + 32], target);   // release (separate line)
    }
  } else if (threadIdx.x == 0) {
    st32sc(&bar[blockIdx.x], target);                // arrival
    while (ld32sc(&bar[GBLK + 32]) < target)
      __builtin_amdgcn_s_sleep(2);
  }
  __syncthreads();
}

// Swizzled chunk layout for [rows][32] bf16 tiles staged as 16B chunks:
// chunk S holds (row = S>>2, k8 = ((S&3) - ((S>>3)&3)) & 3).
// reader for (row,k8): S = row*4 + ((k8 + (row>>1)) & 3)  -> 2-way banks (free).

struct PK {
  const u16 *W6, *Wp1, *Wq1h, *Wp2, *Wq2, *Winp, *QE;
  const float *b_ih, *b_hh, *bp1, *bq1, *bp2, *bq2, *b_in;
  const float *init_deter, *actions, *nonterm, *noise_p, *noise_q;
  u16 *xbuf, *hbuf;    // per-step unique buffers, row stride HLD
  float *out;
  u32 *bar;
};

__global__ __launch_bounds__(256, 1) void rssm_persist(PK p)
{
  __shared__ char smem[65536] __attribute__((aligned(16)));

  const int bid = blockIdx.x, tid = threadIdx.x;
  const int lane = tid & 63, w = tid >> 6;
  const int r16 = lane & 15, k8g = lane >> 4;

  // phase A: 2-D XCD-affine mapping. XCD = bid%8 = (my%4)*2 + (nx%2).
  const int xg = bid & 7, gg = bid >> 3;
  const int my = (gg & 3) * 4 + (xg >> 1);
  const int nx = (gg >> 2) * 2 + (xg & 1);
  const int Am0 = my * 64, An0 = nx * 64;
  const int wr = w >> 1, wc = w & 1;
  const int srow = tid >> 2;
  const int sk8 = ((tid & 3) - ((tid >> 3) & 3)) & 3;
  const int lo = w * 1024;
  const u16* bw[6];
#pragma unroll
  for (int s = 0; s < 6; s++)
    bw[s] = p.W6 + (size_t)s * NP * DP + (size_t)(An0 + srow) * DP + sk8 * 8;
  const size_t aoff = (size_t)(Am0 + srow) * HLD + sk8 * 8;

  // phase B config (heads for 16-row slice x head), bid 0..127
  const bool doB = bid < 128;
  const int slice = bid >> 1, head = bid & 1;
  const int Bm0 = slice * 16;
  const u16* W1 = head ? p.Wq1h : p.Wp1;
  const float* b1 = head ? p.bq1 : p.bp1;
  const u16* W2 = head ? p.Wq2 : p.Wp2;
  const float* b2 = head ? p.bq2 : p.bp2;

  u16* hsl = (u16*)smem;                     // [16][616] bf16
  u16* ph  = (u16*)(smem + 19712);           // [16][648] bf16
  float* red = (float*)(smem + 40448);       // [3][64][16] f32
  u16* xin = (u16*)(smem + 52736);           // [16][72] bf16

  for (int t = 0; t < NT; ++t) {
    const u16* hprev = p.hbuf + (size_t)t * HXS2;
    u16* hnow = p.hbuf + (size_t)(t + 1) * HXS2;
    const u16* xcur = p.xbuf + (size_t)t * HXS2;
    u16* xnxt = p.xbuf + (size_t)(t + 1) * HXS2;
    float* out_t = p.out + (size_t)t * NB * OUTW;

    // =================== phase A: GRU ===================
    {
      const u16* axp = xcur + aoff;
      const u16* ahp = hprev + aoff;
      auto ldsT = [&](int buf, int tile) -> char* { return smem + buf * 32768 + tile * 4096; };
      f32x4 acc[6][2][2] = {};
      auto stage = [&](int buf, int kc) {
        gll16(axp + kc, ldsT(buf, 0) + lo);
        gll16(ahp + kc, ldsT(buf, 1) + lo);
#pragma unroll
        for (int s = 0; s < 6; s++) gll16(bw[s] + kc, ldsT(buf, 2 + s) + lo);
      };
      auto compute = [&](int buf) {
        bf16x8 ax_[2], ah_[2];
#pragma unroll
        for (int i = 0; i < 2; i++) {
          int row = wr * 32 + i * 16 + r16;
          int S = row * 4 + ((k8g + (row >> 1)) & 3);
          ax_[i] = *(const bf16x8*)(ldsT(buf, 0) + S * 16);
          ah_[i] = *(const bf16x8*)(ldsT(buf, 1) + S * 16);
        }
#pragma unroll
        for (int s = 0; s < 6; s++) {
#pragma unroll
          for (int j = 0; j < 2; j++) {
            int row = wc * 32 + j * 16 + r16;
            int S = row * 4 + ((k8g + (row >> 1)) & 3);
            bf16x8 b = *(const bf16x8*)(ldsT(buf, 2 + s) + S * 16);
#pragma unroll
            for (int i = 0; i < 2; i++)
              acc[s][i][j] = __builtin_amdgcn_mfma_f32_16x16x32_bf16(
                  (s < 3) ? ax_[i] : ah_[i], b, acc[s][i][j], 0, 0, 0);
          }
        }
      };
      stage(0, 0);
      for (int it = 0; it < 19; ++it) {
        if (it + 1 < 19) {
          stage((it + 1) & 1, (it + 1) * 32);
          asm volatile("s_waitcnt vmcnt(8)" ::: "memory");
        } else {
          asm volatile("s_waitcnt vmcnt(0)" ::: "memory");
        }
        __builtin_amdgcn_s_barrier();
        __builtin_amdgcn_sched_barrier(0);
        compute(it & 1);
        __builtin_amdgcn_s_barrier();
      }
      const float* dprev = t ? (out_t - (size_t)NB * OUTW) : p.init_deter;
      const int dstr = t ? OUTW : DET;
#pragma unroll
      for (int j = 0; j < 2; j++) {
        int n = An0 + wc * 32 + j * 16 + r16;
        bool nok = (n < DET);
        float bihr = nok ? p.b_ih[n] : 0.f, bhhr = nok ? p.b_hh[n] : 0.f;
        float bihz = nok ? p.b_ih[600 + n] : 0.f, bhhz = nok ? p.b_hh[600 + n] : 0.f;
        float bihn = nok ? p.b_ih[1200 + n] : 0.f, bhhn = nok ? p.b_hh[1200 + n] : 0.f;
#pragma unroll
        for (int i = 0; i < 2; i++) {
          int mb = Am0 + wr * 32 + i * 16 + k8g * 4;
#pragma unroll
          for (int r = 0; r < 4; r++) {
            int m = mb + r;
            // dprev: written by THIS block last step (static mapping) -> L2 hit
            float dp = nok ? dprev[(size_t)m * dstr + n] : 0.f;
            float rg = sigm(acc[0][i][j][r] + bihr + acc[3][i][j][r] + bhhr);
            float zg = sigm(acc[1][i][j][r] + bihz + acc[4][i][j][r] + bhhz);
            float ng = tanhf(acc[2][i][j][r] + bihn + rg * (acc[5][i][j][r] + bhhn));
            float h = (1.f - zg) * ng + zg * dp;
            u32 hb16 = f2bf(h);
            u32 other = (u32)__shfl_xor((int)hb16, 1, 64);
            if (nok) {
              out_t[(size_t)m * OUTW + n] = h;      // plain: same-block reuse only
              if (!(lane & 1))                      // hnow: cross-XCD -> SC store
                st32sc((u32*)&hnow[(size_t)m * HLD + n], hb16 | (other << 16));
            }
          }
        }
      }
    }
    gridbar(p.bar, 2 * t + 1);

    // =================== phase B: heads + sampling + xnext ===================
    if (doB) {
      const bool donext = (t + 1 < NT);
      const float* noise = (head ? p.noise_q : p.noise_p) + (size_t)t * NB * 32;

      // stage h slice [16][608] -> hsl [16][616] (plain cached; virgin lines -> L3)
      {
        const u16* hrow = hnow + (size_t)Bm0 * HLD;
#pragma unroll
        for (int c = 0; c < 5; ++c) {
          int chunk = c * 256 + tid;
          char* ldst = (char*)hsl + (c * 256 + w * 64) * 16;
          if (chunk < 1232) {
            int row = chunk / 77, cc = chunk - row * 77;
            int scc = cc < 76 ? cc : 75;
            gll16(hrow + (size_t)row * HLD + scc * 8, ldst);
          }
        }
      }
      // QE prefetch (overlaps staging + heads1)
      float qe[10][4] = {};
      if (head) {
        const u16* qbase = p.QE + ((size_t)t * NB + Bm0) * NP;
#pragma unroll
        for (int i = 0; i < 10; i++) {
          int j = w + i * 4;
          if (j < 38) {
            int n = j * 16 + r16;
#pragma unroll
            for (int r = 0; r < 4; r++)
              qe[i][r] = bf2f(qbase[(size_t)(k8g * 4 + r) * NP + n]);
          }
        }
      }
      for (int i = tid; i < 320; i += 256) {
        int r = i / 20, c = i - r * 20;
        *(u32*)&ph[r * 648 + 608 + 2 * c] = 0;
      }
      if (donext)
        for (int i = tid; i < 576; i += 256) ((u32*)xin)[i] = 0;
      __syncthreads();

      // heads1: A from LDS, W1 direct-global (L2-resident, head<->XCD parity)
      f32x4 a1[10] = {};
      for (int kc = 0; kc < DP; kc += 32) {
        bf16x8 fa = *(const bf16x8*)&hsl[r16 * 616 + kc + k8g * 8];
#pragma unroll
        for (int i = 0; i < 10; i++) {
          int j = w + i * 4;
          if (j < 38) {
            bf16x8 fb = *(const bf16x8*)&W1[(size_t)(j * 16 + r16) * DP + kc + k8g * 8];
            a1[i] = __builtin_amdgcn_mfma_f32_16x16x32_bf16(fa, fb, a1[i], 0, 0, 0);
          }
        }
      }
#pragma unroll
      for (int i = 0; i < 10; i++) {
        int j = w + i * 4;
        if (j >= 38) break;
        int n = j * 16 + r16;
#pragma unroll
        for (int r = 0; r < 4; r++) {
          int mrow = k8g * 4 + r;
          float v = a1[i][r];
          if (n < DET) {
            v += b1[n] + qe[i][r];
            ph[mrow * 648 + n] = f2bf(eluf(v));
          } else {
            ph[mrow * 648 + n] = 0;
          }
        }
      }
      __syncthreads();
      // heads2: K=640 split over 4 waves, LDS reduce
      f32x4 a2[4] = {};
      {
        int kc0 = w * 160;
#pragma unroll
        for (int ks = 0; ks < 5; ks++) {
          int kc = kc0 + ks * 32;
          bf16x8 fa = *(const bf16x8*)&ph[r16 * 648 + kc + k8g * 8];
#pragma unroll
          for (int j = 0; j < 4; j++) {
            bf16x8 fb = *(const bf16x8*)&W2[(size_t)(j * 16 + r16) * NP + kc + k8g * 8];
            a2[j] = __builtin_amdgcn_mfma_f32_16x16x32_bf16(fa, fb, a2[j], 0, 0, 0);
          }
        }
      }
      if (w) {
#pragma unroll
        for (int j = 0; j < 4; j++)
#pragma unroll
          for (int r = 0; r < 4; r++)
            red[(w - 1) * 1024 + (j * 16 + r16) * 16 + k8g * 4 + r] = a2[j][r];
      }
      __syncthreads();
      if (w == 0) {
#pragma unroll
        for (int j = 0; j < 4; j++)
#pragma unroll
          for (int r = 0; r < 4; r++) {
            int c = j * 16 + r16, mr = k8g * 4 + r;
            a2[j][r] += red[c * 16 + mr] + red[1024 + c * 16 + mr] + red[2048 + c * 16 + mr];
          }
        const int ob = head ? 696 : 600;
        const float* ntn = donext ? p.nonterm + (size_t)(t + 1) * NB : nullptr;
#pragma unroll
        for (int j = 0; j < 2; j++) {
          int c = j * 16 + r16;
          float bmu = b2[c], bsd = b2[32 + c];
#pragma unroll
          for (int r = 0; r < 4; r++) {
            int mr = k8g * 4 + r, m = Bm0 + mr;
            float mu = a2[j][r] + bmu;
            float sd = softplusf(a2[j + 2][r] + bsd) + 0.1f;
            float st = mu + sd * noise[(size_t)m * 32 + c];
            float* op = out_t + (size_t)m * OUTW + ob;
            op[c] = mu; op[32 + c] = sd; op[64 + c] = st;
            if (head && donext) xin[mr * 72 + c] = f2bf(st * ntn[m]);
          }
        }
      } else if (w == 1 && head && donext) {
        const float* an = p.actions + (size_t)(t + 1) * NB * 6;
#pragma unroll
        for (int rep = 0; rep < 2; rep++) {
          int idx = lane + rep * 64;
          if (idx < 96) {
            int rr = idx / 6, c = idx - rr * 6;
            xin[rr * 72 + 32 + c] = f2bf(an[(size_t)(Bm0 + rr) * 6 + c]);
          }
        }
      }
      if (head && donext) {
        __syncthreads();
        f32x4 xc[10] = {};
        const int nb = w * 160;
#pragma unroll
        for (int kc = 0; kc < 64; kc += 32) {
          bf16x8 fa = *(const bf16x8*)&xin[r16 * 72 + kc + k8g * 8];
#pragma unroll
          for (int j = 0; j < 10; j++) {
            bf16x8 fb = *(const bf16x8*)&p.Winp[(size_t)(nb + j * 16 + r16) * 64 + kc + k8g * 8];
            xc[j] = __builtin_amdgcn_mfma_f32_16x16x32_bf16(fa, fb, xc[j], 0, 0, 0);
          }
        }
#pragma unroll
        for (int j = 0; j < 10; j++) {
          int n = nb + j * 16 + r16;
          bool nok = (n < DET);
          float bi = nok ? p.b_in[n] : 0.f;
#pragma unroll
          for (int r = 0; r < 4; r++) {
            int m = Bm0 + k8g * 4 + r;
            float v = eluf(xc[j][r] + bi);
            u32 xb16 = f2bf(v);
            u32 other = (u32)__shfl_xor((int)xb16, 1, 64);
            if (nok && !(lane & 1))                 // xnxt: cross-XCD -> SC store
              st32sc((u32*)&xnxt[(size_t)m * HLD + n], xb16 | (other << 16));
          }
        }
      }
    }
    if (t + 1 < NT) gridbar(p.bar, 2 * t + 2);
  }
}

// ---------------- prolog GEMM (QE, x0) ---------------------------------------
struct GemmZ {
  const u16* A; int lda;
  const u16* B; int ldb;
  int K;
  const float* bias;
  u16* C; int ldc;
  int mode;
};

__global__ __launch_bounds__(256, 2) void gemmP(GemmZ g)
{
  __shared__ u16 lA[2][128 * 32];
  __shared__ u16 lB[2][128 * 32];
  const int tid = threadIdx.x, lane = tid & 63, w = tid >> 6;
  const int wr = w >> 1, wc = w & 1;
  const size_t m0 = (size_t)blockIdx.y * 128;
  const int n0 = blockIdx.x * 128;
  const int r16 = lane & 15, k8g = lane >> 4;
  f32x4 acc[4][4] = {};

  const int S0 = tid, S1 = tid + 256;
  const int ar0 = S0 >> 2, ak0 = (((S0 & 3) - ((S0 >> 3) & 3)) & 3) * 8;
  const int ar1 = S1 >> 2, ak1 = (((S1 & 3) - ((S1 >> 3) & 3)) & 3) * 8;
  const int lo = w * 1024;
  const int niter = g.K / 32;

  auto stage = [&](int buf, int kc) {
    gll16(g.A + (m0 + ar0) * (size_t)g.lda + kc + ak0, (char*)lA[buf] + lo);
    gll16(g.A + (m0 + ar1) * (size_t)g.lda + kc + ak1, (char*)lA[buf] + 4096 + lo);
    gll16(g.B + (size_t)(n0 + ar0) * g.ldb + kc + ak0, (char*)lB[buf] + lo);
    gll16(g.B + (size_t)(n0 + ar1) * g.ldb + kc + ak1, (char*)lB[buf] + 4096 + lo);
  };
  auto compute = [&](int buf) {
    bf16x8 fa[4], fb[4];
#pragma unroll
    for (int i = 0; i < 4; i++) {
      int row = wr * 64 + i * 16 + r16;
      int S = row * 4 + ((k8g + (row >> 1)) & 3);
      fa[i] = *(const bf16x8*)((const char*)lA[buf] + S * 16);
    }
#pragma unroll
    for (int j = 0; j < 4; j++) {
      int row = wc * 64 + j * 16 + r16;
      int S = row * 4 + ((k8g + (row >> 1)) & 3);
      fb[j] = *(const bf16x8*)((const char*)lB[buf] + S * 16);
    }
#pragma unroll
    for (int i = 0; i < 4; i++)
#pragma unroll
      for (int j = 0; j < 4; j++)
        acc[i][j] = __builtin_amdgcn_mfma_f32_16x16x32_bf16(fa[i], fb[j], acc[i][j], 0, 0, 0);
  };

  stage(0, 0);
  __syncthreads();
  for (int it = 0; it < niter; ++it) {
    if (it + 1 < niter) stage((it + 1) & 1, (it + 1) * 32);
    compute(it & 1);
    __syncthreads();
  }

#pragma unroll
  for (int i = 0; i < 4; i++) {
    size_t mb = m0 + wr * 64 + i * 16 + k8g * 4;
#pragma unroll
    for (int j = 0; j < 4; j++) {
      int n = n0 + wc * 64 + j * 16 + r16;
      if (g.mode == 1) {
        if (n >= DP) continue;
        float b = (n < DET) ? g.bias[n] : 0.f;
#pragma unroll
        for (int r = 0; r < 4; r++)
          g.C[(mb + r) * (size_t)g.ldc + n] = f2bf(eluf(acc[i][j][r] + b));
      } else {
        if (n >= g.ldc) continue;
#pragma unroll
        for (int r = 0; r < 4; r++)
          g.C[(mb + r) * (size_t)g.ldc + n] = f2bf(acc[i][j][r]);
      }
    }
  }
}

// ---------------- small prolog kernels ---------------------------------------
__global__ void wconv_k(const float* src, int srows, int scols, int sstride,
                        u16* dst, int drows, int dstride, int c0, int cw)
{
  int idx = blockIdx.x * 256 + threadIdx.x;
  if (idx >= drows * cw) return;
  int r = idx / cw, c = idx - r * cw;
  float v = (r < srows && c < scols) ? src[(size_t)r * sstride + c] : 0.f;
  dst[(size_t)r * dstride + c0 + c] = f2bf(v);
}

__global__ void conv8_k(const float* src, u16* dst, int n8)
{
  int i = blockIdx.x * 256 + threadIdx.x;
  if (i >= n8) return;
  const float4* s = (const float4*)(src + (size_t)i * 8);
  float4 f0 = s[0], f1 = s[1];
  union { u16 h[8]; int4 v; } cv;
  cv.h[0] = f2bf(f0.x); cv.h[1] = f2bf(f0.y); cv.h[2] = f2bf(f0.z); cv.h[3] = f2bf(f0.w);
  cv.h[4] = f2bf(f1.x); cv.h[5] = f2bf(f1.y); cv.h[6] = f2bf(f1.z); cv.h[7] = f2bf(f1.w);
  *(int4*)(dst + (size_t)i * 8) = cv.v;
}

__global__ void xin0_k(const float* stoc0, const float* nt0, const float* act0, u16* xing)
{
  int i = blockIdx.x * 256 + threadIdx.x;
  if (i >= NB * 64) return;
  int m = i >> 6, c = i & 63;
  float v = 0.f;
  if (c < 32) v = stoc0[m * 32 + c] * nt0[m];
  else if (c < 38) v = act0[m * 6 + (c - 32)];
  xing[i] = f2bf(v);
}

// ---------------- host --------------------------------------------------------
extern "C" void kernel_launch(void* const* d_in, const int* in_sizes, int n_in,
                              void* d_out, int out_size, void* d_ws, size_t ws_size,
                              hipStream_t stream)
{
  const float* actions    = (const float*)d_in[0];
  const float* nonterm    = (const float*)d_in[1];
  const float* emb        = (const float*)d_in[2];
  const float* noise_p    = (const float*)d_in[3];
  const float* noise_q    = (const float*)d_in[4];
  const float* init_deter = (const float*)d_in[5];
  const float* init_stoc  = (const float*)d_in[6];
  const float* W_in = (const float*)d_in[7];
  const float* b_in = (const float*)d_in[8];
  const float* W_ih = (const float*)d_in[9];
  const float* b_ih = (const float*)d_in[10];
  const float* W_hh = (const float*)d_in[11];
  const float* b_hh = (const float*)d_in[12];
  const float* Wp1 = (const float*)d_in[13];
  const float* bp1 = (const float*)d_in[14];
  const float* Wp2 = (const float*)d_in[15];
  const float* bp2 = (const float*)d_in[16];
  const float* Wq1 = (const float*)d_in[17];
  const float* bq1 = (const float*)d_in[18];
  const float* Wq2 = (const float*)d_in[19];
  const float* bq2 = (const float*)d_in[20];
  float* out = (float*)d_out;

  char* wsp = (char*)d_ws;
  size_t o = 0;
  auto alloc = [&](size_t b) { char* pp = wsp + o; o = (o + b + 255) & ~(size_t)255; return pp; };
  u16* W6   = (u16*)alloc(6ull * NP * DP * 2);
  u16* Wp1p = (u16*)alloc((size_t)NP * DP * 2);
  u16* Wq1h = (u16*)alloc((size_t)NP * DP * 2);
  u16* Wq1e = (u16*)alloc((size_t)NP * EMB * 2);
  u16* Wp2p = (u16*)alloc(64ull * NP * 2);
  u16* Wq2p = (u16*)alloc(64ull * NP * 2);
  u16* Winp = (u16*)alloc((size_t)NP * 64 * 2);
  u16* xing = (u16*)alloc((size_t)NB * 64 * 2);
  u32* barp = (u32*)alloc(4096);
  u16* xbuf = (u16*)alloc(HXS2 * 2 * (NT + 1));
  u16* hbuf = (u16*)alloc(HXS2 * 2 * (NT + 1));
  u16* embb = (u16*)alloc((size_t)NT * NB * EMB * 2);
  u16* QE   = (u16*)alloc((size_t)NT * NB * NP * 2);
  if (o > ws_size) return;

  hipMemsetAsync(barp, 0, 4096, stream);

  auto wcl = [&](const float* src, int sr, int sc, int ss, u16* dst, int dr, int ds, int c0, int cw) {
    int n = dr * cw;
    wconv_k<<<(n + 255) / 256, 256, 0, stream>>>(src, sr, sc, ss, dst, dr, ds, c0, cw);
  };
  for (int s = 0; s < 3; s++) {
    wcl(W_ih + (size_t)s * 600 * 600, 600, 600, 600, W6 + (size_t)s * NP * DP, NP, DP, 0, DP);
    wcl(W_hh + (size_t)s * 600 * 600, 600, 600, 600, W6 + (size_t)(3 + s) * NP * DP, NP, DP, 0, DP);
  }
  wcl(Wp1, 600, 600, 600, Wp1p, NP, DP, 0, DP);
  wcl(Wq1, 600, 600, 1624, Wq1h, NP, DP, 0, DP);
  wcl(Wq1 + 600, 600, 1024, 1624, Wq1e, NP, EMB, 0, EMB);
  wcl(Wp2, 64, 600, 600, Wp2p, 64, NP, 0, NP);
  wcl(Wq2, 64, 600, 600, Wq2p, 64, NP, 0, NP);
  wcl(W_in, 600, 38, 38, Winp, NP, 64, 0, 64);
  wcl(init_deter, 1024, 600, 600, hbuf, 1024, HLD, 0, DP);

  {
    int n8 = NT * NB * EMB / 8;
    conv8_k<<<(n8 + 255) / 256, 256, 0, stream>>>(emb, embb, n8);
    GemmZ gq = { embb, EMB, Wq1e, EMB, EMB, nullptr, QE, NP, 2 };
    gemmP<<<dim3(5, 400, 1), 256, 0, stream>>>(gq);
  }
  xin0_k<<<NB * 64 / 256, 256, 0, stream>>>(init_stoc, nonterm, actions, xing);
  {
    GemmZ gx = { xing, 64, Winp, 64, 64, b_in, xbuf, HLD, 1 };
    gemmP<<<dim3(5, 8, 1), 256, 0, stream>>>(gx);
  }

  PK pk = { W6, Wp1p, Wq1h, Wp2p, Wq2p, Winp, QE,
            b_ih, b_hh, bp1, bq1, bp2, bq2, b_in,
            init_deter, actions, nonterm, noise_p, noise_q,
            xbuf, hbuf, out, barp };
  rssm_persist<<<GBLK, 256, 0, stream>>>(pk);
}